// Round 5
// baseline (1550.038 us; speedup 1.0000x reference)
//
#include <hip/hip_runtime.h>
#include <hip/hip_bf16.h>

// ---------------------------------------------------------------------------
// NeuralComponent_4432406250089: B=16,S=512,DI=64,H=128,DO=64,L=3,M=32
// Round 10: k_lstm anti-remat — r8/r9 both showed VGPR_Count=80 (~32 packed
// uints + overhead): the compiler kept W_hh PACKED and rematerialized the
// bf16 unpack (128 shifts/masks) inside every step. Fix: route every
// unpacked weight through an empty asm ("+v") so the def is opaque and the
// 128 floats must stay allocated (cap 256 at launch_bounds(512,2)).
// Everything else identical to round-8 config (best verified 1459 us).
// ---------------------------------------------------------------------------

typedef short bf16x8 __attribute__((ext_vector_type(8)));
typedef float f32x4 __attribute__((ext_vector_type(4)));
typedef float f32x16 __attribute__((ext_vector_type(16)));

__device__ __forceinline__ float bl(uint u) { return __uint_as_float(u << 16); }
__device__ __forceinline__ float bh(uint u) { return __uint_as_float(u & 0xffff0000u); }
__device__ __forceinline__ float b2f(ushort u) { return __uint_as_float(((uint)u) << 16); }
__device__ __forceinline__ ushort f2b(float f) {
  uint u = __float_as_uint(f);
  u += 0x7fffu + ((u >> 16) & 1u);
  return (ushort)(u >> 16);
}
__device__ __forceinline__ uint cvtpk(float lo, float hi) {
  uint r;
  asm("v_cvt_pk_bf16_f32 %0, %1, %2" : "=v"(r) : "v"(lo), "v"(hi));
  return r;
}
__device__ __forceinline__ float rdl(float v, int lane) {
  return __int_as_float(__builtin_amdgcn_readlane(__float_as_int(v), lane));
}
__device__ __forceinline__ float sigm(float x) { return 1.0f / (1.0f + __expf(-x)); }
__device__ __forceinline__ float tanh_(float x) { float e = __expf(2.0f * x); return 1.0f - 2.0f / (e + 1.0f); }

// DPP rotate-reduce within 16-lane rows (VALU latency, not DS latency)
__device__ __forceinline__ float dppror_add(float v, const int n) {
  int s;
  switch (n) {
    case 1: s = __builtin_amdgcn_update_dpp(0, __float_as_int(v), 0x121, 0xF, 0xF, true); break;
    case 2: s = __builtin_amdgcn_update_dpp(0, __float_as_int(v), 0x122, 0xF, 0xF, true); break;
    case 4: s = __builtin_amdgcn_update_dpp(0, __float_as_int(v), 0x124, 0xF, 0xF, true); break;
    default: s = __builtin_amdgcn_update_dpp(0, __float_as_int(v), 0x128, 0xF, 0xF, true); break;
  }
  return v + __int_as_float(s);
}
__device__ __forceinline__ float dppror_max(float v, const int n) {
  int s;
  switch (n) {
    case 1: s = __builtin_amdgcn_update_dpp(0, __float_as_int(v), 0x121, 0xF, 0xF, true); break;
    case 2: s = __builtin_amdgcn_update_dpp(0, __float_as_int(v), 0x122, 0xF, 0xF, true); break;
    case 4: s = __builtin_amdgcn_update_dpp(0, __float_as_int(v), 0x124, 0xF, 0xF, true); break;
    default: s = __builtin_amdgcn_update_dpp(0, __float_as_int(v), 0x128, 0xF, 0xF, true); break;
  }
  return fmaxf(v, __int_as_float(s));
}
__device__ __forceinline__ float swz16(float v) {
  return __int_as_float(__builtin_amdgcn_ds_swizzle(__float_as_int(v), 0x401F)); // xor lane^16 within 32
}
// full-row fold: every lane gets v[l&31] + v[32+(l&31)] (VALU permlane swap)
__device__ __forceinline__ float fold32_add(float v) {
  int a = __float_as_int(v), b = a;
  asm("v_permlane32_swap_b32 %0, %1" : "+v"(a), "+v"(b));
  return __int_as_float(a) + __int_as_float(b);
}

// ---- workspace offsets (in 4-byte units) ----
#define O_H     ((size_t)0)
#define O_GX    ((size_t)1048576)
#define O_EW    ((size_t)1048576)   // reuse of GX after k_lstm (memrec ew out)
#define O_QCA   ((size_t)1048576)   // reuse after k_snap/k_read
#define O_KCA   ((size_t)2097152)
#define O_VCA   ((size_t)3145728)
#define O_AO    ((size_t)4194304)
#define O_HS    ((size_t)5242880)
#define O_WM    ((size_t)5242880)   // reuse of HS after k_proj
#define O_ST    ((size_t)6291456)   // fused memrec stream: 16*512*384 f32
#define O_Q     ((size_t)9437184)
#define O_WGS   ((size_t)10485760)
#define O_RGS   ((size_t)10493952)
#define O_BQC   ((size_t)10502144)
#define O_MEMA  ((size_t)10502272)
#define O_PWIN  ((size_t)27279488)
#define O_PWL   ((size_t)27283584)
#define O_PWIH  ((size_t)27308160)
#define O_PCMB  ((size_t)27340928)
#define O_PQKV  ((size_t)27373696)
#define O_PWOC  ((size_t)27398272)
#define O_PWOUT ((size_t)27406464)
#define O_PWOWM ((size_t)27410688)
#define O_WQC16 ((size_t)27418880)
#define O_CAN   ((size_t)27427072)  // canonical bf16 inputs start here

#define F4LD(DST, OFS, P) { float4 _f = *(const float4*)(P); DST[(OFS)]=_f.x; DST[(OFS)+1]=_f.y; DST[(OFS)+2]=_f.z; DST[(OFS)+3]=_f.w; }

// ---------------------------------------------------------------------------
// k_cvt: per-block redundant dtype detection on x, then convert this block's
// assigned input to canonical bf16. grid = dim3(36, 16).
struct CV { const void* src; uint dst; uint n; };
struct CVA { CV d[36]; };
__global__ __launch_bounds__(256) void k_cvt(CVA a, ushort* cb)
{
  __shared__ int flag;
  int tid = threadIdx.x;
  const ushort* xu = (const ushort*)a.d[0].src;
  if (tid < 64) {
    int sane = 0;
    for (int i = tid; i < 512; i += 64) {
      int e = (xu[2 * i] >> 7) & 0xFF;
      sane += (e >= 0x70 && e <= 0x8E) ? 1 : 0;
    }
#pragma unroll
    for (int d = 1; d < 64; d <<= 1) sane += __shfl_xor(sane, d, 64);
    if (tid == 0) flag = (sane > 256) ? 0 : 1;   // 0 = buffer already bf16, 1 = f32
  }
  __syncthreads();
  int isf32 = flag;
  CV c = a.d[blockIdx.x];
  ushort* dst = cb + c.dst;
  uint start = blockIdx.y * 256 + tid, stride = gridDim.y * 256;
  if (isf32) {
    const float* s = (const float*)c.src;
    for (uint j = start; j < c.n; j += stride) dst[j] = f2b(s[j]);
  } else {
    const ushort* s = (const ushort*)c.src;
    for (uint j = start; j < c.n; j += stride) dst[j] = s[j];
  }
}

// ---------------------------------------------------------------------------
__global__ __launch_bounds__(256) void k_wqcomb(const ushort* __restrict__ Wqkv, const ushort* __restrict__ Wrh,
                                                const ushort* __restrict__ brh, const ushort* __restrict__ bqkv,
                                                ushort* __restrict__ wqc, float* __restrict__ bqc)
{
  __shared__ float qr[2][128];
  int tid = threadIdx.x;
  int r = tid >> 7, e = tid & 127;
  int j = blockIdx.x * 2 + r;
  qr[r][e] = b2f(Wqkv[j * 128 + e]);
  __syncthreads();
  float acc = 0.f;
  for (int k = 0; k < 128; ++k) acc += qr[r][k] * b2f(Wrh[k * 128 + e]);
  wqc[j * 128 + e] = f2b(acc);
  if (e == 0) {
    float s = 0.f;
    for (int k = 0; k < 128; ++k) s += qr[r][k] * b2f(brh[k]);
    bqc[j] = s + b2f(bqkv[j]);
  }
}

// ---------------------------------------------------------------------------
struct PD { const ushort* src; uint* dst; int R, C2, RT, base; };
struct PA { PD d[12]; };
__global__ __launch_bounds__(256) void k_pack(PA a)
{
  int p = blockIdx.x >> 5, sl = blockIdx.x & 31;
  PD q = a.d[p];
  for (int d2 = sl; d2 < q.C2; d2 += 32)
    for (int j = threadIdx.x; j < q.R; j += 256)
      q.dst[(size_t)d2 * q.RT + q.base + j] = *(const uint*)(q.src + (size_t)j * q.C2 * 2 + d2 * 2);
}

// ---------------------------------------------------------------------------
__device__ __forceinline__ void mlp_layer(float& h0, float& h1, const uint* wp, const float* bias, int li, int l)
{
  float t0 = bias[(1 + li) * 128 + l], t1 = bias[(1 + li) * 128 + 64 + l];
#pragma unroll
  for (int d2 = 0; d2 < 64; ++d2) {
    float s0 = rdl(d2 < 32 ? h0 : h1, (2 * d2) & 63);
    float s1 = rdl(d2 < 32 ? h0 : h1, (2 * d2 + 1) & 63);
    uint u0 = wp[d2 * 128 + l], u1 = wp[d2 * 128 + 64 + l];
    t0 += s0 * bl(u0) + s1 * bh(u0);
    t1 += s0 * bl(u1) + s1 * bh(u1);
  }
  t0 = fmaxf(t0, 0.f); t1 = fmaxf(t1, 0.f);
  float sm = t0 + t1, sq = t0 * t0 + t1 * t1;
#pragma unroll
  for (int d = 1; d < 64; d <<= 1) { sm += __shfl_xor(sm, d, 64); sq += __shfl_xor(sq, d, 64); }
  float mn = sm * 0.0078125f;
  float var = sq * 0.0078125f - mn * mn;
  float rstd = rsqrtf(var + 1e-5f);
  float ng0 = bias[(4 + li) * 128 + l], ng1 = bias[(4 + li) * 128 + 64 + l];
  float nb0 = bias[(7 + li) * 128 + l], nb1 = bias[(7 + li) * 128 + 64 + l];
  h0 = (t0 - mn) * rstd * ng0 + nb0 + h0;
  h1 = (t1 - mn) * rstd * ng1 + nb1 + h1;
}

__global__ __launch_bounds__(256, 1) void k_mlp(const ushort* __restrict__ x, const uint* __restrict__ pk,
    const ushort* __restrict__ b_in, const ushort* __restrict__ b_l, const ushort* __restrict__ g_l,
    const ushort* __restrict__ be_l, float* __restrict__ h_all)
{
  __shared__ uint lds[12288];
  __shared__ float bias[1280];
  int tid = threadIdx.x;
  for (int i = tid; i < 12288; i += 256) lds[i] = pk[i];         // W_in (4096) + L0 (8192)
  for (int i = tid; i < 1280; i += 256) {
    int which = i >> 7, e = i & 127;
    float v;
    if (which == 0) v = b2f(b_in[e]);
    else if (which < 4) v = b2f(b_l[(which - 1) * 128 + e]);
    else if (which < 7) v = b2f(g_l[(which - 4) * 128 + e]);
    else v = b2f(be_l[(which - 7) * 128 + e]);
    bias[i] = v;
  }
  __syncthreads();
  int wv = tid >> 6, l = tid & 63;
  float h0a[8], h1a[8];
#pragma unroll
  for (int ps = 0; ps < 8; ++ps) {
    int tok = blockIdx.x * 32 + ps * 4 + wv;
    float xv = b2f(x[(size_t)tok * 64 + l]);
    float h0 = bias[l], h1 = bias[64 + l];
#pragma unroll
    for (int d2 = 0; d2 < 32; ++d2) {
      float s0 = rdl(xv, 2 * d2), s1 = rdl(xv, 2 * d2 + 1);
      uint u0 = lds[d2 * 128 + l], u1 = lds[d2 * 128 + 64 + l];
      h0 += s0 * bl(u0) + s1 * bh(u0);
      h1 += s0 * bl(u1) + s1 * bh(u1);
    }
    mlp_layer(h0, h1, lds + 4096, bias, 0, l);
    h0a[ps] = h0; h1a[ps] = h1;
  }
  __syncthreads();
  for (int i = tid; i < 8192; i += 256) lds[i] = pk[12288 + i];  // L1
  __syncthreads();
#pragma unroll
  for (int ps = 0; ps < 8; ++ps) {
    float h0 = h0a[ps], h1 = h1a[ps];
    mlp_layer(h0, h1, lds, bias, 1, l);
    h0a[ps] = h0; h1a[ps] = h1;
  }
  __syncthreads();
  for (int i = tid; i < 8192; i += 256) lds[i] = pk[20480 + i];  // L2
  __syncthreads();
#pragma unroll
  for (int ps = 0; ps < 8; ++ps) {
    int tok = blockIdx.x * 32 + ps * 4 + wv;
    float h0 = h0a[ps], h1 = h1a[ps];
    mlp_layer(h0, h1, lds, bias, 2, l);
    h_all[(size_t)tok * 128 + l] = h0;
    h_all[(size_t)tok * 128 + 64 + l] = h1;
  }
}

// ---------------------------------------------------------------------------
__global__ __launch_bounds__(256, 1) void k_gates(const float* __restrict__ h_all, const uint* __restrict__ pk,
    const ushort* __restrict__ b_ih, const ushort* __restrict__ b_hh, float* __restrict__ gx)
{
  __shared__ uint lds[8192];
  __shared__ float biasg[512];
  int tid = threadIdx.x;
  for (int i = tid; i < 512; i += 256) biasg[i] = b2f(b_ih[i]) + b2f(b_hh[i]);
  int wv = tid >> 6, l = tid & 63;
  for (int s = 0; s < 4; ++s) {
    __syncthreads();
    for (int i = tid; i < 8192; i += 256) { int d2 = i >> 7, j = i & 127; lds[i] = pk[d2 * 512 + s * 128 + j]; }
    __syncthreads();
    for (int ps = 0; ps < 8; ++ps) {
      int tok = blockIdx.x * 32 + ps * 4 + wv;
      float h0 = h_all[(size_t)tok * 128 + l], h1 = h_all[(size_t)tok * 128 + 64 + l];
      float a0 = biasg[s * 128 + l], a1 = biasg[s * 128 + 64 + l];
#pragma unroll
      for (int d2 = 0; d2 < 64; ++d2) {
        float s0 = rdl(d2 < 32 ? h0 : h1, (2 * d2) & 63);
        float s1 = rdl(d2 < 32 ? h0 : h1, (2 * d2 + 1) & 63);
        uint u0 = lds[d2 * 128 + l], u1 = lds[d2 * 128 + 64 + l];
        a0 += s0 * bl(u0) + s1 * bh(u0);
        a1 += s0 * bl(u1) + s1 * bh(u1);
      }
      gx[(size_t)tok * 512 + s * 128 + l] = a0;
      gx[(size_t)tok * 512 + s * 128 + 64 + l] = a1;
    }
  }
}

// ---------------------------------------------------------------------------
// k_lstm: 512 thr, one gate row/thread. Weights unpacked to 8 named f32x16
// AND forced through empty asm ("+v") so the unpack cannot be rematerialized
// in-loop (r8/r9 VGPR=80 proved packed-uint + in-loop re-unpack). hs broadcast
// via 32 uniform ds_read_b128. Two barriers per step.
__global__ __launch_bounds__(512, 2) void k_lstm(const float* __restrict__ gx, const ushort* __restrict__ Whh,
                                                 float* __restrict__ hs_all)
{
  __shared__ __align__(16) float hsl[128];   // hidden state
  __shared__ float gact[512];                // activated gates
  int tid = threadIdx.x;
  int b = blockIdx.x;
  f32x16 wA, wB, wC, wD, wE, wF, wG, wH;     // weight row, dims 0..127
  {
    const uint* rp = (const uint*)(Whh + (size_t)tid * 128);
    uint4 uq;
#define LD16(V, OFS) \
    uq = *(const uint4*)(rp + (OFS)); \
    V[0]=bl(uq.x); V[1]=bh(uq.x); V[2]=bl(uq.y); V[3]=bh(uq.y); \
    V[4]=bl(uq.z); V[5]=bh(uq.z); V[6]=bl(uq.w); V[7]=bh(uq.w); \
    uq = *(const uint4*)(rp + (OFS) + 4); \
    V[8]=bl(uq.x); V[9]=bh(uq.x); V[10]=bl(uq.y); V[11]=bh(uq.y); \
    V[12]=bl(uq.z); V[13]=bh(uq.z); V[14]=bl(uq.w); V[15]=bh(uq.w);
    LD16(wA, 0)  LD16(wB, 8)  LD16(wC, 16) LD16(wD, 24)
    LD16(wE, 32) LD16(wF, 40) LD16(wG, 48) LD16(wH, 56)
#undef LD16
  }
  // anti-remat fence: defs become opaque; allocator must keep 128 floats live
#define KEEP16(V) { \
    float k0=V[0],k1=V[1],k2=V[2],k3=V[3],k4=V[4],k5=V[5],k6=V[6],k7=V[7]; \
    float k8=V[8],k9=V[9],k10=V[10],k11=V[11],k12=V[12],k13=V[13],k14=V[14],k15=V[15]; \
    asm volatile("" : "+v"(k0),"+v"(k1),"+v"(k2),"+v"(k3),"+v"(k4),"+v"(k5),"+v"(k6),"+v"(k7)); \
    asm volatile("" : "+v"(k8),"+v"(k9),"+v"(k10),"+v"(k11),"+v"(k12),"+v"(k13),"+v"(k14),"+v"(k15)); \
    V[0]=k0;V[1]=k1;V[2]=k2;V[3]=k3;V[4]=k4;V[5]=k5;V[6]=k6;V[7]=k7; \
    V[8]=k8;V[9]=k9;V[10]=k10;V[11]=k11;V[12]=k12;V[13]=k13;V[14]=k14;V[15]=k15; }
  KEEP16(wA) KEEP16(wB) KEEP16(wC) KEEP16(wD)
  KEEP16(wE) KEEP16(wF) KEEP16(wG) KEEP16(wH)
#undef KEEP16
  if (tid < 128) hsl[tid] = 0.f;
  float cs = 0.f;                          // live in i-rows (tid<128)
  const float* gbase = gx + (size_t)b * 512 * 512;
  float gcur = gbase[tid];
  int grp = tid >> 7;                      // 0=i 1=f 2=g 3=o (wave-uniform)
  __syncthreads();
  for (int t = 0; t < 512; ++t) {
    float gnext = 0.f;
    if (t < 511) gnext = gbase[(size_t)(t + 1) * 512 + tid];
    float ax = gcur, ay = 0.f, az = 0.f, aw = 0.f;
    float4 s4;
#define DOT4(V, J0, OFS) \
    s4 = *(const float4*)(hsl + (OFS)); \
    ax = fmaf(V[(J0)+0], s4.x, ax); ay = fmaf(V[(J0)+1], s4.y, ay); \
    az = fmaf(V[(J0)+2], s4.z, az); aw = fmaf(V[(J0)+3], s4.w, aw);
    DOT4(wA, 0, 0)   DOT4(wA, 4, 4)   DOT4(wA, 8, 8)    DOT4(wA, 12, 12)
    DOT4(wB, 0, 16)  DOT4(wB, 4, 20)  DOT4(wB, 8, 24)   DOT4(wB, 12, 28)
    DOT4(wC, 0, 32)  DOT4(wC, 4, 36)  DOT4(wC, 8, 40)   DOT4(wC, 12, 44)
    DOT4(wD, 0, 48)  DOT4(wD, 4, 52)  DOT4(wD, 8, 56)   DOT4(wD, 12, 60)
    DOT4(wE, 0, 64)  DOT4(wE, 4, 68)  DOT4(wE, 8, 72)   DOT4(wE, 12, 76)
    DOT4(wF, 0, 80)  DOT4(wF, 4, 84)  DOT4(wF, 8, 88)   DOT4(wF, 12, 92)
    DOT4(wG, 0, 96)  DOT4(wG, 4, 100) DOT4(wG, 8, 104)  DOT4(wG, 12, 108)
    DOT4(wH, 0, 112) DOT4(wH, 4, 116) DOT4(wH, 8, 120)  DOT4(wH, 12, 124)
#undef DOT4
    float a = (ax + ay) + (az + aw);
    gact[tid] = (grp == 2) ? tanh_(a) : sigm(a);
    __syncthreads();                       // gates ready; hsl reads done
    if (tid < 128) {
      float si = gact[tid], sf = gact[128 + tid], tg = gact[256 + tid], so = gact[384 + tid];
      cs = sf * cs + si * tg;
      float hv = so * tanh_(cs);
      hsl[tid] = hv;
      hs_all[((size_t)b * 512 + t) * 128 + tid] = hv;
    }
    gcur = gnext;
    __syncthreads();                       // hsl ready for next step
  }
}

// ---------------------------------------------------------------------------
// k_proj: s=0 wk -> ST[0..128) + rg; s=1 wv -> gv=wg*wv -> ST[256..384);
// s=2 ev=sigm -> ST[128..256); s=3 q -> q_a. ST row = 384 f32 per (b,t).
__global__ __launch_bounds__(256, 1) void k_proj(const float* __restrict__ hs_all, const uint* __restrict__ pk,
    const ushort* __restrict__ bwh, const ushort* __restrict__ beh, const float* __restrict__ bqc,
    const ushort* __restrict__ wrg, const ushort* __restrict__ brg, const ushort* __restrict__ wwg,
    const ushort* __restrict__ bwg,
    float* __restrict__ st, float* __restrict__ q_a, float* __restrict__ rg_a)
{
  __shared__ uint lds[8192];
  __shared__ float biasc[512];
  int tid = threadIdx.x;
  for (int i = tid; i < 512; i += 256)
    biasc[i] = (i < 256) ? b2f(bwh[i]) : (i < 384) ? b2f(beh[i - 256]) : bqc[i - 384];
  float brgv = b2f(brg[0]), bwgv = b2f(bwg[0]);
  int wv = tid >> 6, l = tid & 63;
  for (int s = 0; s < 4; ++s) {
    __syncthreads();
    for (int i = tid; i < 8192; i += 256) { int d2 = i >> 7, j = i & 127; lds[i] = pk[d2 * 512 + s * 128 + j]; }
    __syncthreads();
    for (int ps = 0; ps < 8; ++ps) {
      int tok = blockIdx.x * 32 + ps * 4 + wv;
      float h0 = hs_all[(size_t)tok * 128 + l], h1 = hs_all[(size_t)tok * 128 + 64 + l];
      float a0 = biasc[s * 128 + l], a1 = biasc[s * 128 + 64 + l];
#pragma unroll
      for (int d2 = 0; d2 < 64; ++d2) {
        float s0 = rdl(d2 < 32 ? h0 : h1, (2 * d2) & 63);
        float s1 = rdl(d2 < 32 ? h0 : h1, (2 * d2 + 1) & 63);
        uint u0 = lds[d2 * 128 + l], u1 = lds[d2 * 128 + 64 + l];
        a0 += s0 * bl(u0) + s1 * bh(u0);
        a1 += s0 * bl(u1) + s1 * bh(u1);
      }
      if (s == 0) {
        st[(size_t)tok * 384 + l] = a0;
        st[(size_t)tok * 384 + 64 + l] = a1;
        float pr = h0 * b2f(wrg[l]) + h1 * b2f(wrg[64 + l]);
#pragma unroll
        for (int d = 1; d < 64; d <<= 1) pr += __shfl_xor(pr, d, 64);
        if (l == 0) rg_a[tok] = sigm(pr + brgv);
      } else if (s == 1) {
        float pw = h0 * b2f(wwg[l]) + h1 * b2f(wwg[64 + l]);
#pragma unroll
        for (int d = 1; d < 64; d <<= 1) pw += __shfl_xor(pw, d, 64);
        float wg = sigm(pw + bwgv);
        st[(size_t)tok * 384 + 256 + l] = wg * a0;
        st[(size_t)tok * 384 + 256 + 64 + l] = wg * a1;
      } else if (s == 2) {
        st[(size_t)tok * 384 + 128 + l] = sigm(a0);
        st[(size_t)tok * 384 + 128 + 64 + l] = sigm(a1);
      } else {
        q_a[(size_t)tok * 128 + l] = a0;
        q_a[(size_t)tok * 128 + 64 + l] = a1;
      }
    }
  }
}

// ---------------------------------------------------------------------------
// k_memrec: one wave per batch. Lane l: row r=l&31, half h=l>>5, mem state in
// FOUR NAMED f32x16 vectors (64 VGPRs, spill-proof). Dot lane-local; halves
// folded via v_permlane32_swap (VALU). Softmax den: DPP ror + one ds_swizzle;
// lazy exp offset. Outputs ONLY ew[t][m] (128 B/step); snapshots in k_snap.
__global__ __launch_bounds__(64, 1) void k_memrec(const float* __restrict__ st, const ushort* __restrict__ mem0,
    float* __restrict__ ew_all)
{
  __shared__ __align__(16) float sbuf[2][384];
  int l = threadIdx.x;
  int b = blockIdx.x;
  int r = l & 31, h = l >> 5;
  f32x16 mA, mB, mC, mD;   // local dims 0..63 = global dims h*64 + (0..63) of row r
  {
    const uint* m0 = (const uint*)mem0 + r * 64 + 32 * h;
    uint4 uq;
#define LD16(V, OFS) \
    uq = *(const uint4*)(m0 + (OFS)); \
    V[0]=bl(uq.x); V[1]=bh(uq.x); V[2]=bl(uq.y); V[3]=bh(uq.y); \
    V[4]=bl(uq.z); V[5]=bh(uq.z); V[6]=bl(uq.w); V[7]=bh(uq.w); \
    uq = *(const uint4*)(m0 + (OFS) + 4); \
    V[8]=bl(uq.x); V[9]=bh(uq.x); V[10]=bl(uq.y); V[11]=bh(uq.y); \
    V[12]=bl(uq.z); V[13]=bh(uq.z); V[14]=bl(uq.w); V[15]=bh(uq.w);
    LD16(mA, 0) LD16(mB, 8) LD16(mC, 16) LD16(mD, 24)
#undef LD16
  }
  const float* stb = st + (size_t)b * 512 * 384;
  {
    float4 a = *(const float4*)(stb + 4 * l);
    float2 c = *(const float2*)(stb + 256 + 2 * l);
    *(float4*)(&sbuf[0][4 * l]) = a;
    *(float2*)(&sbuf[0][256 + 2 * l]) = c;
  }
  float moff = 0.f;
  float* ewp = ew_all + (size_t)b * 512 * 32 + r;
  for (int t = 0; t < 512; ++t) {
    int cur = t & 1, nxt = cur ^ 1;
    // prefetch next step's fused stream (registers; L2-resident)
    float4 ga = make_float4(0.f, 0.f, 0.f, 0.f);
    float2 gc = make_float2(0.f, 0.f);
    if (t < 511) {
      const float* sp = stb + (size_t)(t + 1) * 384;
      ga = *(const float4*)(sp + 4 * l);
      gc = *(const float2*)(sp + 256 + 2 * l);
    }
    // lane-local dot over this half's 64 dims (LDS broadcast reads)
    const float* wkp = &sbuf[cur][h * 64];
    float dx = 0.f, dy = 0.f, dz = 0.f, dw = 0.f;
    float4 w4;
#define DOT4(V, J0, OFS) \
    w4 = *(const float4*)(wkp + (OFS)); \
    dx = fmaf(w4.x, V[(J0)+0], dx); dy = fmaf(w4.y, V[(J0)+1], dy); \
    dz = fmaf(w4.z, V[(J0)+2], dz); dw = fmaf(w4.w, V[(J0)+3], dw);
    DOT4(mA, 0, 0)  DOT4(mA, 4, 4)  DOT4(mA, 8, 8)   DOT4(mA, 12, 12)
    DOT4(mB, 0, 16) DOT4(mB, 4, 20) DOT4(mB, 8, 24)  DOT4(mB, 12, 28)
    DOT4(mC, 0, 32) DOT4(mC, 4, 36) DOT4(mC, 8, 40)  DOT4(mC, 12, 44)
    DOT4(mD, 0, 48) DOT4(mD, 4, 52) DOT4(mD, 8, 56)  DOT4(mD, 12, 60)
#undef DOT4
    float dp = (dx + dy) + (dz + dw);
    dp = fold32_add(dp);                   // full row-dot in every lane (VALU)
    // softmax with lazy offset; den via DPP ror-reduce + one xor16 swizzle
    float e = __expf(dp - moff);
    float s16 = dppror_add(dppror_add(dppror_add(dppror_add(e, 1), 2), 4), 8);
    float den = s16 + swz16(s16);
    float ew = e / den;
    float x16 = dppror_max(dppror_max(dppror_max(dppror_max(dp, 1), 2), 4), 8);
    // update: mem += ew*(gv - ev*mem)
    const float* evp = &sbuf[cur][128 + h * 64];
    const float* gvp = &sbuf[cur][256 + h * 64];
    float4 e4, g4;
#define UPD4(V, J0, OFS) \
    e4 = *(const float4*)(evp + (OFS)); g4 = *(const float4*)(gvp + (OFS)); \
    V[(J0)+0] = fmaf(ew, fmaf(-e4.x, V[(J0)+0], g4.x), V[(J0)+0]); \
    V[(J0)+1] = fmaf(ew, fmaf(-e4.y, V[(J0)+1], g4.y), V[(J0)+1]); \
    V[(J0)+2] = fmaf(ew, fmaf(-e4.z, V[(J0)+2], g4.z), V[(J0)+2]); \
    V[(J0)+3] = fmaf(ew, fmaf(-e4.w, V[(J0)+3], g4.w), V[(J0)+3]);
    UPD4(mA, 0, 0)  UPD4(mA, 4, 4)  UPD4(mA, 8, 8)   UPD4(mA, 12, 12)
    UPD4(mB, 0, 16) UPD4(mB, 4, 20) UPD4(mB, 8, 24)  UPD4(mB, 12, 28)
    UPD4(mC, 0, 32) UPD4(mC, 4, 36) UPD4(mC, 8, 40)  UPD4(mC, 12, 44)
    UPD4(mD, 0, 48) UPD4(mD, 4, 52) UPD4(mD, 8, 56)  UPD4(mD, 12, 60)
#undef UPD4
    // stage t+1 into the other LDS buffer
    if (t < 511) {
      *(float4*)(&sbuf[nxt][4 * l]) = ga;
      *(float2*)(&sbuf[nxt][256 + 2 * l]) = gc;
    }
    // emit ew (the only recurrence output; snapshots replayed by k_snap)
    if (l < 32) ewp[(size_t)t * 32] = ew;
    moff = fmaxf(x16, swz16(x16));
  }
}

// ---------------------------------------------------------------------------
// k_snap: parallel elementwise replay of the mem recurrence. Thread = (b,m,d2)
// chain; identical fmaf order as k_memrec -> bitwise-identical snapshots.
// grid = 16 batches * 8 blocks, 256 thr; writes bf16-packed mem_all.
__global__ __launch_bounds__(256, 1) void k_snap(const float* __restrict__ st, const float* __restrict__ ew_all,
    const ushort* __restrict__ mem0, uint* __restrict__ mem_all)
{
  int b = blockIdx.x >> 3;
  int j = ((blockIdx.x & 7) << 8) + threadIdx.x;   // 0..2047
  int m = j >> 6, d2 = j & 63;
  uint u0 = ((const uint*)mem0)[(m << 6) + d2];
  float s0 = bl(u0), s1 = bh(u0);
  const float* ep = st + (size_t)b * 512 * 384 + 128 + 2 * d2;
  const float* gp = ep + 128;
  const float* ap = ew_all + (size_t)b * 512 * 32 + m;
  uint* mb = mem_all + (size_t)b * 512 * 2048 + (m << 6) + d2;
  for (int t = 0; t < 512; t += 4) {
    float2 eA = *(const float2*)(ep + (size_t)(t + 0) * 384);
    float2 eB = *(const float2*)(ep + (size_t)(t + 1) * 384);
    float2 eC = *(const float2*)(ep + (size_t)(t + 2) * 384);
    float2 eD = *(const float2*)(ep + (size_t)(t + 3) * 384);
    float2 gA = *(const float2*)(gp + (size_t)(t + 0) * 384);
    float2 gB = *(const float2*)(gp + (size_t)(t + 1) * 384);
    float2 gC = *(const float2*)(gp + (size_t)(t + 2) * 384);
    float2 gD = *(const float2*)(gp + (size_t)(t + 3) * 384);
    float a0 = ap[(size_t)(t + 0) * 32];
    float a1 = ap[(size_t)(t + 1) * 32];
    float a2 = ap[(size_t)(t + 2) * 32];
    float a3 = ap[(size_t)(t + 3) * 32];
    mb[(size_t)(t + 0) * 2048] = cvtpk(s0, s1);
    s0 = fmaf(a0, fmaf(-eA.x, s0, gA.x), s0);
    s1 = fmaf(a0, fmaf(-eA.y, s1, gA.y), s1);
    mb[(size_t)(t + 1) * 2048] = cvtpk(s0, s1);
    s0 = fmaf(a1, fmaf(-eB.x, s0, gB.x), s0);
    s1 = fmaf(a1, fmaf(-eB.y, s1, gB.y), s1);
    mb[(size_t)(t + 2) * 2048] = cvtpk(s0, s1);
    s0 = fmaf(a2, fmaf(-eC.x, s0, gC.x), s0);
    s1 = fmaf(a2, fmaf(-eC.y, s1, gC.y), s1);
    mb[(size_t)(t + 3) * 2048] = cvtpk(s0, s1);
    s0 = fmaf(a3, fmaf(-eD.x, s0, gD.x), s0);
    s1 = fmaf(a3, fmaf(-eD.y, s1, gD.y), s1);
  }
}

// ---------------------------------------------------------------------------
__global__ __launch_bounds__(256, 1) void k_read(const ushort* __restrict__ Wqkv, const ushort* __restrict__ bwo,
    const uint* __restrict__ wo_pk, const uint* __restrict__ mem_all, const float* __restrict__ q_all,
    const float* __restrict__ rg_all, const float* __restrict__ h_all, float* __restrict__ wm_all)
{
  __shared__ float Kl[32 * 133];
  __shared__ float Vl[32 * 133];
  __shared__ __align__(16) char ml[8192];
  __shared__ float ql[128];
  __shared__ float ol[128];
  __shared__ float part[256];
  int tid = threadIdx.x, l = tid & 63, w = tid >> 6;
  int b = blockIdx.x >> 6, c = blockIdx.x & 63;
  int mat = w >> 1, chh = w & 1;
  bf16x8 bfr[4][4];
#pragma unroll
  for (int ct = 0; ct < 4; ++ct)
#pragma unroll
    for (int kt = 0; kt < 4; ++kt) {
      int j = chh * 64 + ct * 16 + (l & 15);
      bfr[ct][kt] = *(const bf16x8*)(Wqkv + (size_t)(128 + mat * 128 + j) * 128 + kt * 32 + (l >> 4) * 8);
    }
  for (int s8 = 0; s8 < 8; ++s8) {
    int t = c * 8 + s8;
    size_t bt = (size_t)b * 512 + t;
    {
      const uint4* src = (const uint4*)(mem_all + bt * 2048);
      uint4 v0 = src[tid * 2], v1 = src[tid * 2 + 1];
      int row = tid >> 3;
      int b0 = row * 256 + (tid & 7) * 32;
      int sw = (row & 7) << 4;
      *(uint4*)(ml + (b0 ^ sw)) = v0;
      *(uint4*)(ml + ((b0 + 16) ^ sw)) = v1;
    }
    if (tid < 128) ql[tid] = q_all[bt * 128 + tid];
    __syncthreads();
    f32x4 acc[2][4];
#pragma unroll
    for (int rt = 0; rt < 2; ++rt)
#pragma unroll
      for (int ct = 0; ct < 4; ++ct) { f32x4 z = {0.f, 0.f, 0.f, 0.f}; acc[rt][ct] = z; }
    bf16x8 af[2][4];
#pragma unroll
    for (int rt = 0; rt < 2; ++rt)
#pragma unroll
      for (int kt = 0; kt < 4; ++kt) {
        int row = rt * 16 + (l & 15);
        int byte0 = (row * 256 + kt * 64 + (l >> 4) * 16) ^ ((row & 7) << 4);
        af[rt][kt] = *(const bf16x8*)(ml + byte0);
      }
#pragma unroll
    for (int rt = 0; rt < 2; ++rt)
#pragma unroll
      for (int ct = 0; ct < 4; ++ct)
#pragma unroll
        for (int kt = 0; kt < 4; ++kt)
          acc[rt][ct] = __builtin_amdgcn_mfma_f32_16x16x32_bf16(af[rt][kt], bfr[ct][kt], acc[rt][ct], 0, 0, 0);
    {
      float* dst = mat ? Vl : Kl;
#pragma unroll
      for (int rt = 0; rt < 2; ++rt)
#pragma unroll
        for (int ct = 0; ct < 4; ++ct)
#pragma unroll
          for (int rr = 0; rr < 4; ++rr) {
            int row = rt * 16 + (l >> 4) * 4 + rr;
            int col = chh * 64 + ct * 16 + (l & 15);
            dst[row * 133 + col] = acc[rt][ct][rr];
          }
    }
    __syncthreads();
    {
      int hh = w;
      float qv[16];
#pragma unroll
      for (int q = 0; q < 4; ++q) { F4LD(qv, 4 * q, ql + hh * 32 + (l >> 5) * 16 + 4 * q); }
      int m = l & 31;
      float sv = 0.f;
#pragma unroll
      for (int i = 0; i < 16; ++i) sv += qv[i] * Kl[m * 133 + hh * 32 + (l >> 5) * 16 + i];
      sv += __shfl_xor(sv, 32, 64);
      sv *= 0.1767766952966369f;
      float mx = sv;
      mx = fmaxf(mx, __shfl_xor(mx, 1, 64)); mx = fmaxf(mx, __shfl_xor(mx, 2, 64));
      mx = fmaxf(mx, __shfl_xor(mx, 4, 64)); mx = fmaxf(mx, __shfl_xor(mx, 8, 64));
      mx = fmaxf(mx, __shfl_xor(mx, 16, 64));
      float e = __expf(sv - mx);
      float den = e;
      den += __shfl_xor(den, 1, 64); den += __shfl_xor(den, 2, 64); den += __shfl_xor(den, 4, 64);
      den += __shfl_xor(den, 8, 64); den += __shfl_xor(den, 16, 64);
      float a = e / den;
      float o = 0.f;
      int dpos = l & 31, mh = l >> 5;
#pragma unroll
      for (int i = 0; i < 16; ++i) {
        int mm = mh * 16 + i;
        float am = __shfl(a, mm, 64);
        o += am * Vl[mm * 133 + hh * 32 + dpos];
      }
      o += __shfl_xor(o, 32, 64);
      if (l < 32) ol[hh * 32 + dpos] = o;
    }
    __syncthreads();
    {
      int j = tid & 127, dh = tid >> 7;
      float o0 = ol[l], o1 = ol[64 + l];
      float pa = 0.f;
#pragma unroll
      for (int i2 = 0; i2 < 32; ++i2) {
        int d2 = dh * 32 + i2;
        float s0, s1;
        if (dh == 0) { s0 = rdl(o0, 2 * i2); s1 = rdl(o0, 2 * i2 + 1); }
        else { s0 = rdl(o1, 2 * i2); s1 = rdl(o1, 2 * i2 + 1); }
        uint u = wo_pk[d2 * 128 + j];
        pa += s0 * bl(u) + s1 * bh(u);
      }
      part[tid] = pa;
    }
    __syncthreads();
    if (tid < 128) {
      float ro = part[tid] + part[tid + 128] + b2f(bwo[tid]);
      float rg = rg_all[bt];
      wm_all[bt * 128 + tid] = h_all[bt * 128 + tid] + rg * ro;
    }
    __syncthreads();
  }
}

// ---------------------------------------------------------------------------
__global__ __launch_bounds__(256, 1) void k_caqkv(const float* __restrict__ wm, const uint* __restrict__ pk,
    const ushort* __restrict__ bqkv, float* __restrict__ qca, float* __restrict__ kca, float* __restrict__ vca)
{
  __shared__ uint lds[8192];
  int tid = threadIdx.x;
  int wv = tid >> 6, l = tid & 63;
  for (int s = 0; s < 3; ++s) {
    __syncthreads();
    for (int i = tid; i < 8192; i += 256) { int d2 = i >> 7, j = i & 127; lds[i] = pk[d2 * 384 + s * 128 + j]; }
    __syncthreads();
    for (int ps = 0; ps < 8; ++ps) {
      int tok = blockIdx.x * 32 + ps * 4 + wv;
      int b = tok >> 9, ss = tok & 511;
      float h0 = wm[(size_t)tok * 128 + l], h1 = wm[(size_t)tok * 128 + 64 + l];
      float a0 = b2f(bqkv[s * 128 + l]), a1 = b2f(bqkv[s * 128 + 64 + l]);
#pragma unroll
      for (int d2 = 0; d2 < 64; ++d2) {
        float s0 = rdl(d2 < 32 ? h0 : h1, (2 * d2) & 63);
        float s1 = rdl(d2 < 32 ? h0 : h1, (2 * d2 + 1) & 63);
        uint u0 = lds[d2 * 128 + l], u1 = lds[d2 * 128 + 64 + l];
        a0 += s0 * bl(u0) + s1 * bh(u0);
        a1 += s0 * bl(u1) + s1 * bh(u1);
      }
#pragma unroll
      for (int k = 0; k < 2; ++k) {
        int j = l + 64 * k;
        int hd = j >> 4, dd = j & 15;
        size_t idx = ((size_t)(b * 8 + hd) * 512 + ss) * 16 + dd;
        float v = k == 0 ? a0 : a1;
        if (s == 0) qca[idx] = v * 0.25f;
        else if (s == 1) kca[idx] = v;
        else vca[idx] = v;
      }
    }
  }
}

// ---------------------------------------------------------------------------
__global__ __launch_bounds__(256, 1) void k_caattn(const float* __restrict__ qca, const float* __restrict__ kca,
    const float* __restrict__ vca, float* __restrict__ ao)
{
  __shared__ float kl[8192];       // K f32
  __shared__ uint vl[4096];        // V packed bf16 pairs
  int tid = threadIdx.x;
  int bh_ = blockIdx.x >> 1, half = blockIdx.x & 1;
  for (int i = tid; i < 8192; i += 256) kl[i] = kca[(size_t)bh_ * 8192 + i];
  for (int i = tid; i < 4096; i += 256) {
    float v0 = vca[(size_t)bh_ * 8192 + 2 * i], v1 = vca[(size_t)bh_ * 8192 + 2 * i + 1];
    vl[i] = (uint)f2b(v0) | ((uint)f2b(v1) << 16);
  }
  __syncthreads();
  int r = half * 256 + tid;
  float qv[16];
#pragma unroll
  for (int q = 0; q < 4; ++q) { F4LD(qv, 4 * q, qca + (size_t)bh_ * 8192 + r * 16 + 4 * q); }
  float o[16];
#pragma unroll
  for (int i = 0; i < 16; ++i) o[i] = 0.f;
  float mx = -3e38f, den = 0.f;
  for (int ch = 0; ch < 8; ++ch) {
    float sc[64];
#pragma unroll
    for (int m2 = 0; m2 < 64; ++m2) {
      const float* kr = kl + (ch * 64 + m2) * 16;
      float s = 0.f;
#pragma unroll
      for (int i = 0; i < 16; ++i) s += qv[i] * kr[i];
      sc[m2] = s;
    }
    float cm = sc[0];
#pragma unroll
    for (int m2 = 1; m2 < 64; ++m2) cm = fmaxf(cm, sc[m2]);
    if (cm > mx) {
      float rs = __expf(mx - cm);
      den *= rs;
#pragma unroll
      for (int i = 0; i < 16; ++i) o[i] *= rs;
      mx = cm;
    }
#pragma unroll
    for (int m2 = 0; m2 < 64; ++m2) {
      float e = __expf(sc[m2] - mx);
      den += e;
      const uint* vr = vl + (ch * 64 + m2) * 8;
#pragma unroll
      for (int i = 0; i < 8; ++i) {
        uint u = vr[i];
        o[2 * i] += e * bl(u);
        o[2 * i + 1] += e * bh(u);
      }
    }
  }
  float rd = 1.f / den;
#pragma unroll
  for (int q = 0; q < 4; ++q) {
    float4 f = make_float4(o[4 * q] * rd, o[4 * q + 1] * rd, o[4 * q + 2] * rd, o[4 * q + 3] * rd);
    *(float4*)(ao + (size_t)bh_ * 8192 + r * 16 + 4 * q) = f;
  }
}

// ---------------------------------------------------------------------------
__global__ __launch_bounds__(256, 1) void k_cafinal(const float* __restrict__ wm, const float* __restrict__ ao,
    const uint* __restrict__ pko, const uint* __restrict__ pkout,
    const ushort* __restrict__ wai, const ushort* __restrict__ bai, const ushort* __restrict__ gca,
    const ushort* __restrict__ beca, const ushort* __restrict__ boca, const ushort* __restrict__ bout,
    float* __restrict__ out)
{
  __shared__ uint lds[12288];
  __shared__ float fb[576];
  int tid = threadIdx.x;
  for (int i = tid; i < 8192; i += 256) lds[i] = pko[i];
  for (int i = tid; i < 4096; i += 256) lds[8192 + i] = pkout[i];
  for (int i = tid; i < 576; i += 256) {
    float v;
    if (i < 128) v = b2f(wai[i]);
    else if (i < 256) v = b2f(gca[i - 128]);
    else if (i < 384) v = b2f(beca[i - 256]);
    else if (i < 512) v = b2f(boca[i - 384]);
    else v = b2f(bout[i - 512]);
    fb[i] = v;
  }
  __syncthreads();
  float baiv = b2f(bai[0]);
  int wv = tid >> 6, l = tid & 63;
  for (int ps = 0; ps < 8; ++ps) {
    int tok = blockIdx.x * 32 + ps * 4 + wv;
    int b = tok >> 9, s = tok & 511;
    float w0 = wm[(size_t)tok * 128 + l], w1 = wm[(size_t)tok * 128 + 64 + l];
    float o0 = ao[((size_t)(b * 8 + (l >> 4)) * 512 + s) * 16 + (l & 15)];
    float o1 = ao[((size_t)(b * 8 + 4 + (l >> 4)) * 512 + s) * 16 + (l & 15)];
    float ip = w0 * fb[l] + w1 * fb[64 + l];
#pragma unroll
    for (int d = 1; d < 64; d <<= 1) ip += __shfl_xor(ip, d, 64);
    float it = sigm(ip + baiv);
    float a0 = fb[384 + l], a1 = fb[384 + 64 + l];
#pragma unroll
    for (int d2 = 0; d2 < 64; ++d2) {
      float s0 = rdl(d2 < 32 ? o0 : o1, (2 * d2) & 63);
      float s1 = rdl(d2 < 32 ? o0 : o1, (2 * d2 + 1) & 63);
      uint u0 = lds[d2 * 128 + l], u1 = lds[d2 * 128 + 64 + l];
      a0 += s0 * bl(u0) + s1 * bh(u0);
      a1 += s0 * bl(u1) + s1 * bh(u1);
    }
    float x0 = a0 * it + w0, x1 = a1 * it + w1;
    float smv = x0 + x1, sq = x0 * x0 + x1 * x1;
#pragma unroll
    for (int d = 1; d < 64; d <<= 1) { smv += __shfl_xor(smv, d, 64); sq += __shfl_xor(sq, d, 64); }
    float mn = smv * 0.0078125f;
    float var = sq * 0.0078125f - mn * mn;
    float rstd = rsqrtf(var + 1e-5f);
    float c0 = (x0 - mn) * rstd * fb[128 + l] + fb[256 + l];
    float c1 = (x1 - mn) * rstd * fb[128 + 64 + l] + fb[256 + 64 + l];
    float ob = fb[512 + l];
#pragma unroll
    for (int d2 = 0; d2 < 64; ++d2) {
      float s0 = rdl(d2 < 32 ? c0 : c1, (2 * d2) & 63);
      float s1 = rdl(d2 < 32 ? c0 : c1, (2 * d2 + 1) & 63);
      uint u = lds[8192 + d2 * 64 + l];
      ob += s0 * bl(u) + s1 * bh(u);
    }
    out[(size_t)tok * 64 + l] = ob;   // f32 output (reference output dtype)
  }
}

// ---------------------------------------------------------------------------
extern "C" void kernel_launch(void* const* d_in, const int* in_sizes, int n_in,
                              void* d_out, int out_size, void* d_ws, size_t ws_size,
                              hipStream_t stream)
{
  (void)out_size; (void)ws_size;
  float* ws = (float*)d_ws;
  uint* wsu = (uint*)d_ws;
  ushort* cb = (ushort*)(wsu + O_CAN);

  // canonical bf16 copies of all inputs (16B-aligned offsets)
  uint off[36]; uint cum = 0;
  for (int i = 0; i < 36; ++i) { off[i] = cum; cum = (cum + (uint)in_sizes[i] + 7u) & ~7u; }

  CVA ca;
  for (int i = 0; i < 36; ++i) ca.d[i] = CV{ d_in[i], off[i], (uint)in_sizes[i] };
  k_cvt<<<dim3(36, 16), 256, 0, stream>>>(ca, cb);

  const ushort* x        = cb + off[0];
  const ushort* W_in     = cb + off[1];
  const ushort* b_in     = cb + off[2];
  const ushort* W_l      = cb + off[3];
  const ushort* b_l      = cb + off[4];
  const ushort* g_l      = cb + off[5];
  const ushort* be_l     = cb + off[6];
  const ushort* W_ih     = cb + off[7];
  const ushort* W_hh     = cb + off[8];
  const ushort* b_ih     = cb + off[9];
  const ushort* b_hh     = cb + off[10];
  const ushort* mem0     = cb + off[11];
  const ushort* W_rh     = cb + off[12];
  const ushort* b_rh     = cb + off[13];
  const ushort* W_wh     = cb + off[14];
  const ushort* b_wh     = cb + off[15];
  const ushort* W_eh     = cb + off[16];
  const ushort* b_eh     = cb + off[17];
  const ushort* W_rg     = cb + off[18];
  const ushort* b_rg     = cb + off[19];
  const ushort* W_wg     = cb + off[20];
  const ushort* b_wg     = cb + off[21];
  const ushort* W_wm_qkv = cb + off[22];
  const ushort* b_wm_qkv = cb + off[23];
  const ushort* W_wm_o   = cb + off[24];
  const ushort* b_wm_o   = cb + off[25];
  const ushort* W_ca_qkv = cb + off[26];
  const ushort* b_ca_qkv = cb + off[27];
  const ushort* W_ca_o   = cb + off[28];
  const ushort* b_ca_o   = cb + off[29];
  const ushort* W_ai     = cb + off[30];
  const ushort* b_ai     = cb + off[31];
  const ushort* g_ca     = cb + off[32];
  const ushort* be_ca    = cb + off[33];
  const ushort* W_out    = cb + off[34];
  const ushort* b_out    = cb + off[35];

  k_wqcomb<<<64, 256, 0, stream>>>(W_wm_qkv, W_rh, b_rh, b_wm_qkv, (ushort*)(wsu + O_WQC16), ws + O_BQC);

  PA pa;
  pa.d[0]  = PD{ W_in,                       wsu + O_PWIN,  128, 32, 128, 0 };
  pa.d[1]  = PD{ W_l,                        wsu + O_PWL,   128, 64, 128, 0 };
  pa.d[2]  = PD{ W_l + 16384,                wsu + O_PWL + 8192,  128, 64, 128, 0 };
  pa.d[3]  = PD{ W_l + 32768,                wsu + O_PWL + 16384, 128, 64, 128, 0 };
  pa.d[4]  = PD{ W_ih,                       wsu + O_PWIH,  512, 64, 512, 0 };
  pa.d[5]  = PD{ W_wh,                       wsu + O_PCMB,  256, 64, 512, 0 };
  pa.d[6]  = PD{ W_eh,                       wsu + O_PCMB,  128, 64, 512, 256 };
  pa.d[7]  = PD{ (const ushort*)(wsu + O_WQC16), wsu + O_PCMB, 128, 64, 512, 384 };
  pa.d[8]  = PD{ W_ca_qkv,                   wsu + O_PQKV,  384, 64, 384, 0 };
  pa.d[9]  = PD{ W_ca_o,                     wsu + O_PWOC,  128, 64, 128, 0 };
  pa.d[10] = PD{ W_out,                      wsu + O_PWOUT,  64, 64,  64, 0 };
  pa.d[11] = PD{ W_wm_o,                     wsu + O_PWOWM, 128, 64, 128, 0 };
  k_pack<<<384, 256, 0, stream>>>(pa);

  k_mlp<<<256, 256, 0, stream>>>(x, wsu + O_PWIN, b_in, b_l, g_l, be_l, ws + O_H);
  k_gates<<<256, 256, 0, stream>>>(ws + O_H, wsu + O_PWIH, b_ih, b_hh, ws + O_GX);
  k_lstm<<<16, 512, 0, stream>>>(ws + O_GX, W_hh, ws + O_HS);
  k_proj<<<256, 256, 0, stream>>>(ws + O_HS, wsu + O_PCMB, b_wh, b_eh, ws + O_BQC,
                                  W_rg, b_rg, W_wg, b_wg,
                                  ws + O_ST, ws + O_Q, ws + O_RGS);
  k_memrec<<<16, 64, 0, stream>>>(ws + O_ST, mem0, ws + O_EW);
  k_snap<<<128, 256, 0, stream>>>(ws + O_ST, ws + O_EW, mem0, wsu + O_MEMA);
  k_read<<<1024, 256, 0, stream>>>(W_wm_qkv, b_wm_o, wsu + O_PWOWM, wsu + O_MEMA,
                                   ws + O_Q, ws + O_RGS, ws + O_H, ws + O_WM);
  k_caqkv<<<256, 256, 0, stream>>>(ws + O_WM, wsu + O_PQKV, b_ca_qkv, ws + O_QCA, ws + O_KCA, ws + O_VCA);
  k_caattn<<<256, 256, 0, stream>>>(ws + O_QCA, ws + O_KCA, ws + O_VCA, ws + O_AO);
  k_cafinal<<<256, 256, 0, stream>>>(ws + O_WM, ws + O_AO, wsu + O_PWOC, wsu + O_PWOUT,
                                     W_ai, b_ai, g_ca, be_ca, b_ca_o, b_out, (float*)d_out);
}

// Round 6
// 1391.557 us; speedup vs baseline: 1.1139x; 1.1139x over previous
//
#include <hip/hip_runtime.h>
#include <hip/hip_bf16.h>

// ---------------------------------------------------------------------------
// NeuralComponent_4432406250089: B=16,S=512,DI=64,H=128,DO=64,L=3,M=32
// Round 11: k_lstm restructured. r8-r10 showed the cost was never weight
// storage (VGPR=80 invariant, FETCH flat): it was the 2-barrier + gact-LDS
// round-trip + 2-waves-only serial segment (~2100cy/step). New layout:
// tid = cell*4+slice; each thread partial-dots ALL 4 gates of its cell over
// a 32-wide k-slice; slice-reduce via DPP quad_perm (VALU); redundant
// per-group cs update; ping-pong hsl -> ONE barrier/step. Weights
// pre-unpacked to f32 by k_whh (nothing to remat). Rest = r8 config.
// ---------------------------------------------------------------------------

typedef short bf16x8 __attribute__((ext_vector_type(8)));
typedef float f32x4 __attribute__((ext_vector_type(4)));
typedef float f32x16 __attribute__((ext_vector_type(16)));

__device__ __forceinline__ float bl(uint u) { return __uint_as_float(u << 16); }
__device__ __forceinline__ float bh(uint u) { return __uint_as_float(u & 0xffff0000u); }
__device__ __forceinline__ float b2f(ushort u) { return __uint_as_float(((uint)u) << 16); }
__device__ __forceinline__ ushort f2b(float f) {
  uint u = __float_as_uint(f);
  u += 0x7fffu + ((u >> 16) & 1u);
  return (ushort)(u >> 16);
}
__device__ __forceinline__ uint cvtpk(float lo, float hi) {
  uint r;
  asm("v_cvt_pk_bf16_f32 %0, %1, %2" : "=v"(r) : "v"(lo), "v"(hi));
  return r;
}
__device__ __forceinline__ float rdl(float v, int lane) {
  return __int_as_float(__builtin_amdgcn_readlane(__float_as_int(v), lane));
}
__device__ __forceinline__ float sigm(float x) { return 1.0f / (1.0f + __expf(-x)); }
__device__ __forceinline__ float tanh_(float x) { float e = __expf(2.0f * x); return 1.0f - 2.0f / (e + 1.0f); }

// DPP rotate-reduce within 16-lane rows (VALU latency, not DS latency)
__device__ __forceinline__ float dppror_add(float v, const int n) {
  int s;
  switch (n) {
    case 1: s = __builtin_amdgcn_update_dpp(0, __float_as_int(v), 0x121, 0xF, 0xF, true); break;
    case 2: s = __builtin_amdgcn_update_dpp(0, __float_as_int(v), 0x122, 0xF, 0xF, true); break;
    case 4: s = __builtin_amdgcn_update_dpp(0, __float_as_int(v), 0x124, 0xF, 0xF, true); break;
    default: s = __builtin_amdgcn_update_dpp(0, __float_as_int(v), 0x128, 0xF, 0xF, true); break;
  }
  return v + __int_as_float(s);
}
__device__ __forceinline__ float dppror_max(float v, const int n) {
  int s;
  switch (n) {
    case 1: s = __builtin_amdgcn_update_dpp(0, __float_as_int(v), 0x121, 0xF, 0xF, true); break;
    case 2: s = __builtin_amdgcn_update_dpp(0, __float_as_int(v), 0x122, 0xF, 0xF, true); break;
    case 4: s = __builtin_amdgcn_update_dpp(0, __float_as_int(v), 0x124, 0xF, 0xF, true); break;
    default: s = __builtin_amdgcn_update_dpp(0, __float_as_int(v), 0x128, 0xF, 0xF, true); break;
  }
  return fmaxf(v, __int_as_float(s));
}
__device__ __forceinline__ float swz16(float v) {
  return __int_as_float(__builtin_amdgcn_ds_swizzle(__float_as_int(v), 0x401F)); // xor lane^16 within 32
}
// full-row fold: every lane gets v[l&31] + v[32+(l&31)] (VALU permlane swap)
__device__ __forceinline__ float fold32_add(float v) {
  int a = __float_as_int(v), b = a;
  asm("v_permlane32_swap_b32 %0, %1" : "+v"(a), "+v"(b));
  return __int_as_float(a) + __int_as_float(b);
}
// quad_perm xor within 4-lane groups (VALU): ctrl 0xB1 = lane^1, 0x4E = lane^2
__device__ __forceinline__ float qx1(float v) {
  return __int_as_float(__builtin_amdgcn_update_dpp(0, __float_as_int(v), 0xB1, 0xF, 0xF, true));
}
__device__ __forceinline__ float qx2(float v) {
  return __int_as_float(__builtin_amdgcn_update_dpp(0, __float_as_int(v), 0x4E, 0xF, 0xF, true));
}

// ---- workspace offsets (in 4-byte units) ----
#define O_H     ((size_t)0)
#define O_GX    ((size_t)1048576)
#define O_EW    ((size_t)1048576)   // reuse of GX after k_lstm (memrec ew out)
#define O_QCA   ((size_t)1048576)   // reuse after k_snap/k_read
#define O_KCA   ((size_t)2097152)
#define O_VCA   ((size_t)3145728)
#define O_AO    ((size_t)4194304)
#define O_WHF   ((size_t)4194304)   // f32 W_hh (64K f32); dead before k_caattn writes AO
#define O_HS    ((size_t)5242880)
#define O_WM    ((size_t)5242880)   // reuse of HS after k_proj
#define O_ST    ((size_t)6291456)   // fused memrec stream: 16*512*384 f32
#define O_Q     ((size_t)9437184)
#define O_WGS   ((size_t)10485760)
#define O_RGS   ((size_t)10493952)
#define O_BQC   ((size_t)10502144)
#define O_MEMA  ((size_t)10502272)
#define O_PWIN  ((size_t)27279488)
#define O_PWL   ((size_t)27283584)
#define O_PWIH  ((size_t)27308160)
#define O_PCMB  ((size_t)27340928)
#define O_PQKV  ((size_t)27373696)
#define O_PWOC  ((size_t)27398272)
#define O_PWOUT ((size_t)27406464)
#define O_PWOWM ((size_t)27410688)
#define O_WQC16 ((size_t)27418880)
#define O_CAN   ((size_t)27427072)  // canonical bf16 inputs start here

#define F4LD(DST, OFS, P) { float4 _f = *(const float4*)(P); DST[(OFS)]=_f.x; DST[(OFS)+1]=_f.y; DST[(OFS)+2]=_f.z; DST[(OFS)+3]=_f.w; }

// ---------------------------------------------------------------------------
// k_cvt: per-block redundant dtype detection on x, then convert this block's
// assigned input to canonical bf16. grid = dim3(36, 16).
struct CV { const void* src; uint dst; uint n; };
struct CVA { CV d[36]; };
__global__ __launch_bounds__(256) void k_cvt(CVA a, ushort* cb)
{
  __shared__ int flag;
  int tid = threadIdx.x;
  const ushort* xu = (const ushort*)a.d[0].src;
  if (tid < 64) {
    int sane = 0;
    for (int i = tid; i < 512; i += 64) {
      int e = (xu[2 * i] >> 7) & 0xFF;
      sane += (e >= 0x70 && e <= 0x8E) ? 1 : 0;
    }
#pragma unroll
    for (int d = 1; d < 64; d <<= 1) sane += __shfl_xor(sane, d, 64);
    if (tid == 0) flag = (sane > 256) ? 0 : 1;   // 0 = buffer already bf16, 1 = f32
  }
  __syncthreads();
  int isf32 = flag;
  CV c = a.d[blockIdx.x];
  ushort* dst = cb + c.dst;
  uint start = blockIdx.y * 256 + tid, stride = gridDim.y * 256;
  if (isf32) {
    const float* s = (const float*)c.src;
    for (uint j = start; j < c.n; j += stride) dst[j] = f2b(s[j]);
  } else {
    const ushort* s = (const ushort*)c.src;
    for (uint j = start; j < c.n; j += stride) dst[j] = s[j];
  }
}

// ---------------------------------------------------------------------------
__global__ __launch_bounds__(256) void k_wqcomb(const ushort* __restrict__ Wqkv, const ushort* __restrict__ Wrh,
                                                const ushort* __restrict__ brh, const ushort* __restrict__ bqkv,
                                                ushort* __restrict__ wqc, float* __restrict__ bqc)
{
  __shared__ float qr[2][128];
  int tid = threadIdx.x;
  int r = tid >> 7, e = tid & 127;
  int j = blockIdx.x * 2 + r;
  qr[r][e] = b2f(Wqkv[j * 128 + e]);
  __syncthreads();
  float acc = 0.f;
  for (int k = 0; k < 128; ++k) acc += qr[r][k] * b2f(Wrh[k * 128 + e]);
  wqc[j * 128 + e] = f2b(acc);
  if (e == 0) {
    float s = 0.f;
    for (int k = 0; k < 128; ++k) s += qr[r][k] * b2f(brh[k]);
    bqc[j] = s + b2f(bqkv[j]);
  }
}

// ---------------------------------------------------------------------------
struct PD { const ushort* src; uint* dst; int R, C2, RT, base; };
struct PA { PD d[12]; };
__global__ __launch_bounds__(256) void k_pack(PA a)
{
  int p = blockIdx.x >> 5, sl = blockIdx.x & 31;
  PD q = a.d[p];
  for (int d2 = sl; d2 < q.C2; d2 += 32)
    for (int j = threadIdx.x; j < q.R; j += 256)
      q.dst[(size_t)d2 * q.RT + q.base + j] = *(const uint*)(q.src + (size_t)j * q.C2 * 2 + d2 * 2);
}

// ---------------------------------------------------------------------------
// k_whh: unpack W_hh bf16 -> f32, per-thread-contiguous layout for k_lstm:
// whf[th*128 + g*32 + kk] = W_hh[(g*128 + c)*128 + s*32 + kk], th = c*4+s.
__global__ __launch_bounds__(256) void k_whh(const ushort* __restrict__ Whh, float* __restrict__ whf)
{
  int e = blockIdx.x * 256 + threadIdx.x;   // 0..65535
  int j = e & 127, th = e >> 7;
  int g = j >> 5, kk = j & 31, c = th >> 2, sl = th & 3;
  whf[e] = b2f(Whh[(g * 128 + c) * 128 + sl * 32 + kk]);
}

// ---------------------------------------------------------------------------
__device__ __forceinline__ void mlp_layer(float& h0, float& h1, const uint* wp, const float* bias, int li, int l)
{
  float t0 = bias[(1 + li) * 128 + l], t1 = bias[(1 + li) * 128 + 64 + l];
#pragma unroll
  for (int d2 = 0; d2 < 64; ++d2) {
    float s0 = rdl(d2 < 32 ? h0 : h1, (2 * d2) & 63);
    float s1 = rdl(d2 < 32 ? h0 : h1, (2 * d2 + 1) & 63);
    uint u0 = wp[d2 * 128 + l], u1 = wp[d2 * 128 + 64 + l];
    t0 += s0 * bl(u0) + s1 * bh(u0);
    t1 += s0 * bl(u1) + s1 * bh(u1);
  }
  t0 = fmaxf(t0, 0.f); t1 = fmaxf(t1, 0.f);
  float sm = t0 + t1, sq = t0 * t0 + t1 * t1;
#pragma unroll
  for (int d = 1; d < 64; d <<= 1) { sm += __shfl_xor(sm, d, 64); sq += __shfl_xor(sq, d, 64); }
  float mn = sm * 0.0078125f;
  float var = sq * 0.0078125f - mn * mn;
  float rstd = rsqrtf(var + 1e-5f);
  float ng0 = bias[(4 + li) * 128 + l], ng1 = bias[(4 + li) * 128 + 64 + l];
  float nb0 = bias[(7 + li) * 128 + l], nb1 = bias[(7 + li) * 128 + 64 + l];
  h0 = (t0 - mn) * rstd * ng0 + nb0 + h0;
  h1 = (t1 - mn) * rstd * ng1 + nb1 + h1;
}

__global__ __launch_bounds__(256, 1) void k_mlp(const ushort* __restrict__ x, const uint* __restrict__ pk,
    const ushort* __restrict__ b_in, const ushort* __restrict__ b_l, const ushort* __restrict__ g_l,
    const ushort* __restrict__ be_l, float* __restrict__ h_all)
{
  __shared__ uint lds[12288];
  __shared__ float bias[1280];
  int tid = threadIdx.x;
  for (int i = tid; i < 12288; i += 256) lds[i] = pk[i];         // W_in (4096) + L0 (8192)
  for (int i = tid; i < 1280; i += 256) {
    int which = i >> 7, e = i & 127;
    float v;
    if (which == 0) v = b2f(b_in[e]);
    else if (which < 4) v = b2f(b_l[(which - 1) * 128 + e]);
    else if (which < 7) v = b2f(g_l[(which - 4) * 128 + e]);
    else v = b2f(be_l[(which - 7) * 128 + e]);
    bias[i] = v;
  }
  __syncthreads();
  int wv = tid >> 6, l = tid & 63;
  float h0a[8], h1a[8];
#pragma unroll
  for (int ps = 0; ps < 8; ++ps) {
    int tok = blockIdx.x * 32 + ps * 4 + wv;
    float xv = b2f(x[(size_t)tok * 64 + l]);
    float h0 = bias[l], h1 = bias[64 + l];
#pragma unroll
    for (int d2 = 0; d2 < 32; ++d2) {
      float s0 = rdl(xv, 2 * d2), s1 = rdl(xv, 2 * d2 + 1);
      uint u0 = lds[d2 * 128 + l], u1 = lds[d2 * 128 + 64 + l];
      h0 += s0 * bl(u0) + s1 * bh(u0);
      h1 += s0 * bl(u1) + s1 * bh(u1);
    }
    mlp_layer(h0, h1, lds + 4096, bias, 0, l);
    h0a[ps] = h0; h1a[ps] = h1;
  }
  __syncthreads();
  for (int i = tid; i < 8192; i += 256) lds[i] = pk[12288 + i];  // L1
  __syncthreads();
#pragma unroll
  for (int ps = 0; ps < 8; ++ps) {
    float h0 = h0a[ps], h1 = h1a[ps];
    mlp_layer(h0, h1, lds, bias, 1, l);
    h0a[ps] = h0; h1a[ps] = h1;
  }
  __syncthreads();
  for (int i = tid; i < 8192; i += 256) lds[i] = pk[20480 + i];  // L2
  __syncthreads();
#pragma unroll
  for (int ps = 0; ps < 8; ++ps) {
    int tok = blockIdx.x * 32 + ps * 4 + wv;
    float h0 = h0a[ps], h1 = h1a[ps];
    mlp_layer(h0, h1, lds, bias, 2, l);
    h_all[(size_t)tok * 128 + l] = h0;
    h_all[(size_t)tok * 128 + 64 + l] = h1;
  }
}

// ---------------------------------------------------------------------------
__global__ __launch_bounds__(256, 1) void k_gates(const float* __restrict__ h_all, const uint* __restrict__ pk,
    const ushort* __restrict__ b_ih, const ushort* __restrict__ b_hh, float* __restrict__ gx)
{
  __shared__ uint lds[8192];
  __shared__ float biasg[512];
  int tid = threadIdx.x;
  for (int i = tid; i < 512; i += 256) biasg[i] = b2f(b_ih[i]) + b2f(b_hh[i]);
  int wv = tid >> 6, l = tid & 63;
  for (int s = 0; s < 4; ++s) {
    __syncthreads();
    for (int i = tid; i < 8192; i += 256) { int d2 = i >> 7, j = i & 127; lds[i] = pk[d2 * 512 + s * 128 + j]; }
    __syncthreads();
    for (int ps = 0; ps < 8; ++ps) {
      int tok = blockIdx.x * 32 + ps * 4 + wv;
      float h0 = h_all[(size_t)tok * 128 + l], h1 = h_all[(size_t)tok * 128 + 64 + l];
      float a0 = biasg[s * 128 + l], a1 = biasg[s * 128 + 64 + l];
#pragma unroll
      for (int d2 = 0; d2 < 64; ++d2) {
        float s0 = rdl(d2 < 32 ? h0 : h1, (2 * d2) & 63);
        float s1 = rdl(d2 < 32 ? h0 : h1, (2 * d2 + 1) & 63);
        uint u0 = lds[d2 * 128 + l], u1 = lds[d2 * 128 + 64 + l];
        a0 += s0 * bl(u0) + s1 * bh(u0);
        a1 += s0 * bl(u1) + s1 * bh(u1);
      }
      gx[(size_t)tok * 512 + s * 128 + l] = a0;
      gx[(size_t)tok * 512 + s * 128 + 64 + l] = a1;
    }
  }
}

// ---------------------------------------------------------------------------
// k_lstm layout-C: tid = c*4+s (128 cells x 4 k-slices). Thread partial-dots
// all 4 gates of cell c over hs[32s..32s+32); slice-reduce via DPP quad_perm;
// all 4 group lanes redundantly update private cs; lane s=0 writes hsl.
// Ping-pong hsl => ONE barrier/step. Weights f32 from k_whh (no remat).
__global__ __launch_bounds__(512, 2) void k_lstm(const float* __restrict__ gx, const float* __restrict__ whf,
                                                 float* __restrict__ hs_all)
{
  __shared__ __align__(16) float hsl[2][128];
  int tid = threadIdx.x;
  int b = blockIdx.x;
  int s = tid & 3, c = tid >> 2;
  f32x16 wA, wB, wC, wD, wE, wF, wG, wH;   // w[g*32+kk]: A,B=g0 C,D=g1 E,F=g2 G,H=g3
  {
    const float4* wp = (const float4*)(whf + (size_t)tid * 128);
    float4 a0, a1, a2, a3;
#define LW16(V, Q) \
    a0 = wp[(Q)]; a1 = wp[(Q) + 1]; a2 = wp[(Q) + 2]; a3 = wp[(Q) + 3]; \
    V[0]=a0.x; V[1]=a0.y; V[2]=a0.z; V[3]=a0.w; V[4]=a1.x; V[5]=a1.y; V[6]=a1.z; V[7]=a1.w; \
    V[8]=a2.x; V[9]=a2.y; V[10]=a2.z; V[11]=a2.w; V[12]=a3.x; V[13]=a3.y; V[14]=a3.z; V[15]=a3.w;
    LW16(wA, 0)  LW16(wB, 4)  LW16(wC, 8)  LW16(wD, 12)
    LW16(wE, 16) LW16(wF, 20) LW16(wG, 24) LW16(wH, 28)
#undef LW16
  }
  if (tid < 128) hsl[0][tid] = 0.f;
  float cs = 0.f;                            // private copy per lane (4x redundant)
  const float* gbase = gx + (size_t)b * 512 * 512 + s * 128 + c;
  float gcur = gbase[0];
  float* hout = hs_all + (size_t)b * 512 * 128 + c;
  __syncthreads();
  for (int t = 0; t < 512; ++t) {
    float gnext = 0.f;
    if (t < 511) gnext = gbase[(size_t)(t + 1) * 512];
    const float* hp = &hsl[t & 1][s * 32];
    float p0 = (s == 0) ? gcur : 0.f;
    float p1 = (s == 1) ? gcur : 0.f;
    float p2 = (s == 2) ? gcur : 0.f;
    float p3 = (s == 3) ? gcur : 0.f;
    float4 h4;
#define DOT4(V0, V1, V2, V3, J, HOFS) \
    h4 = *(const float4*)(hp + (HOFS)); \
    p0 = fmaf(V0[(J)+0], h4.x, p0); p0 = fmaf(V0[(J)+1], h4.y, p0); p0 = fmaf(V0[(J)+2], h4.z, p0); p0 = fmaf(V0[(J)+3], h4.w, p0); \
    p1 = fmaf(V1[(J)+0], h4.x, p1); p1 = fmaf(V1[(J)+1], h4.y, p1); p1 = fmaf(V1[(J)+2], h4.z, p1); p1 = fmaf(V1[(J)+3], h4.w, p1); \
    p2 = fmaf(V2[(J)+0], h4.x, p2); p2 = fmaf(V2[(J)+1], h4.y, p2); p2 = fmaf(V2[(J)+2], h4.z, p2); p2 = fmaf(V2[(J)+3], h4.w, p2); \
    p3 = fmaf(V3[(J)+0], h4.x, p3); p3 = fmaf(V3[(J)+1], h4.y, p3); p3 = fmaf(V3[(J)+2], h4.z, p3); p3 = fmaf(V3[(J)+3], h4.w, p3);
    DOT4(wA, wC, wE, wG, 0, 0)   DOT4(wA, wC, wE, wG, 4, 4)
    DOT4(wA, wC, wE, wG, 8, 8)   DOT4(wA, wC, wE, wG, 12, 12)
    DOT4(wB, wD, wF, wH, 0, 16)  DOT4(wB, wD, wF, wH, 4, 20)
    DOT4(wB, wD, wF, wH, 8, 24)  DOT4(wB, wD, wF, wH, 12, 28)
#undef DOT4
    // slice reduction within 4-lane group (VALU DPP, no LDS)
    p0 += qx1(p0); p0 += qx2(p0);
    p1 += qx1(p1); p1 += qx2(p1);
    p2 += qx1(p2); p2 += qx2(p2);
    p3 += qx1(p3); p3 += qx2(p3);
    // cell update (redundant across the 4 group lanes)
    cs = sigm(p1) * cs + sigm(p0) * tanh_(p2);
    float hv = sigm(p3) * tanh_(cs);
    if (s == 0) {
      hsl[(t + 1) & 1][c] = hv;
      hout[(size_t)t * 128] = hv;
    }
    gcur = gnext;
    __syncthreads();                         // hsl[(t+1)&1] ready for next step
  }
}

// ---------------------------------------------------------------------------
// k_proj: s=0 wk -> ST[0..128) + rg; s=1 wv -> gv=wg*wv -> ST[256..384);
// s=2 ev=sigm -> ST[128..256); s=3 q -> q_a. ST row = 384 f32 per (b,t).
__global__ __launch_bounds__(256, 1) void k_proj(const float* __restrict__ hs_all, const uint* __restrict__ pk,
    const ushort* __restrict__ bwh, const ushort* __restrict__ beh, const float* __restrict__ bqc,
    const ushort* __restrict__ wrg, const ushort* __restrict__ brg, const ushort* __restrict__ wwg,
    const ushort* __restrict__ bwg,
    float* __restrict__ st, float* __restrict__ q_a, float* __restrict__ rg_a)
{
  __shared__ uint lds[8192];
  __shared__ float biasc[512];
  int tid = threadIdx.x;
  for (int i = tid; i < 512; i += 256)
    biasc[i] = (i < 256) ? b2f(bwh[i]) : (i < 384) ? b2f(beh[i - 256]) : bqc[i - 384];
  float brgv = b2f(brg[0]), bwgv = b2f(bwg[0]);
  int wv = tid >> 6, l = tid & 63;
  for (int s = 0; s < 4; ++s) {
    __syncthreads();
    for (int i = tid; i < 8192; i += 256) { int d2 = i >> 7, j = i & 127; lds[i] = pk[d2 * 512 + s * 128 + j]; }
    __syncthreads();
    for (int ps = 0; ps < 8; ++ps) {
      int tok = blockIdx.x * 32 + ps * 4 + wv;
      float h0 = hs_all[(size_t)tok * 128 + l], h1 = hs_all[(size_t)tok * 128 + 64 + l];
      float a0 = biasc[s * 128 + l], a1 = biasc[s * 128 + 64 + l];
#pragma unroll
      for (int d2 = 0; d2 < 64; ++d2) {
        float s0 = rdl(d2 < 32 ? h0 : h1, (2 * d2) & 63);
        float s1 = rdl(d2 < 32 ? h0 : h1, (2 * d2 + 1) & 63);
        uint u0 = lds[d2 * 128 + l], u1 = lds[d2 * 128 + 64 + l];
        a0 += s0 * bl(u0) + s1 * bh(u0);
        a1 += s0 * bl(u1) + s1 * bh(u1);
      }
      if (s == 0) {
        st[(size_t)tok * 384 + l] = a0;
        st[(size_t)tok * 384 + 64 + l] = a1;
        float pr = h0 * b2f(wrg[l]) + h1 * b2f(wrg[64 + l]);
#pragma unroll
        for (int d = 1; d < 64; d <<= 1) pr += __shfl_xor(pr, d, 64);
        if (l == 0) rg_a[tok] = sigm(pr + brgv);
      } else if (s == 1) {
        float pw = h0 * b2f(wwg[l]) + h1 * b2f(wwg[64 + l]);
#pragma unroll
        for (int d = 1; d < 64; d <<= 1) pw += __shfl_xor(pw, d, 64);
        float wg = sigm(pw + bwgv);
        st[(size_t)tok * 384 + 256 + l] = wg * a0;
        st[(size_t)tok * 384 + 256 + 64 + l] = wg * a1;
      } else if (s == 2) {
        st[(size_t)tok * 384 + 128 + l] = sigm(a0);
        st[(size_t)tok * 384 + 128 + 64 + l] = sigm(a1);
      } else {
        q_a[(size_t)tok * 128 + l] = a0;
        q_a[(size_t)tok * 128 + 64 + l] = a1;
      }
    }
  }
}

// ---------------------------------------------------------------------------
// k_memrec: one wave per batch. Lane l: row r=l&31, half h=l>>5, mem state in
// FOUR NAMED f32x16 vectors (64 VGPRs, spill-proof). Dot lane-local; halves
// folded via v_permlane32_swap (VALU). Softmax den: DPP ror + one ds_swizzle;
// lazy exp offset. Outputs ONLY ew[t][m] (128 B/step); snapshots in k_snap.
__global__ __launch_bounds__(64, 1) void k_memrec(const float* __restrict__ st, const ushort* __restrict__ mem0,
    float* __restrict__ ew_all)
{
  __shared__ __align__(16) float sbuf[2][384];
  int l = threadIdx.x;
  int b = blockIdx.x;
  int r = l & 31, h = l >> 5;
  f32x16 mA, mB, mC, mD;   // local dims 0..63 = global dims h*64 + (0..63) of row r
  {
    const uint* m0 = (const uint*)mem0 + r * 64 + 32 * h;
    uint4 uq;
#define LD16(V, OFS) \
    uq = *(const uint4*)(m0 + (OFS)); \
    V[0]=bl(uq.x); V[1]=bh(uq.x); V[2]=bl(uq.y); V[3]=bh(uq.y); \
    V[4]=bl(uq.z); V[5]=bh(uq.z); V[6]=bl(uq.w); V[7]=bh(uq.w); \
    uq = *(const uint4*)(m0 + (OFS) + 4); \
    V[8]=bl(uq.x); V[9]=bh(uq.x); V[10]=bl(uq.y); V[11]=bh(uq.y); \
    V[12]=bl(uq.z); V[13]=bh(uq.z); V[14]=bl(uq.w); V[15]=bh(uq.w);
    LD16(mA, 0) LD16(mB, 8) LD16(mC, 16) LD16(mD, 24)
#undef LD16
  }
  const float* stb = st + (size_t)b * 512 * 384;
  {
    float4 a = *(const float4*)(stb + 4 * l);
    float2 c = *(const float2*)(stb + 256 + 2 * l);
    *(float4*)(&sbuf[0][4 * l]) = a;
    *(float2*)(&sbuf[0][256 + 2 * l]) = c;
  }
  float moff = 0.f;
  float* ewp = ew_all + (size_t)b * 512 * 32 + r;
  for (int t = 0; t < 512; ++t) {
    int cur = t & 1, nxt = cur ^ 1;
    // prefetch next step's fused stream (registers; L2-resident)
    float4 ga = make_float4(0.f, 0.f, 0.f, 0.f);
    float2 gc = make_float2(0.f, 0.f);
    if (t < 511) {
      const float* sp = stb + (size_t)(t + 1) * 384;
      ga = *(const float4*)(sp + 4 * l);
      gc = *(const float2*)(sp + 256 + 2 * l);
    }
    // lane-local dot over this half's 64 dims (LDS broadcast reads)
    const float* wkp = &sbuf[cur][h * 64];
    float dx = 0.f, dy = 0.f, dz = 0.f, dw = 0.f;
    float4 w4;
#define DOT4(V, J0, OFS) \
    w4 = *(const float4*)(wkp + (OFS)); \
    dx = fmaf(w4.x, V[(J0)+0], dx); dy = fmaf(w4.y, V[(J0)+1], dy); \
    dz = fmaf(w4.z, V[(J0)+2], dz); dw = fmaf(w4.w, V[(J0)+3], dw);
    DOT4(mA, 0, 0)  DOT4(mA, 4, 4)  DOT4(mA, 8, 8)   DOT4(mA, 12, 12)
    DOT4(mB, 0, 16) DOT4(mB, 4, 20) DOT4(mB, 8, 24)  DOT4(mB, 12, 28)
    DOT4(mC, 0, 32) DOT4(mC, 4, 36) DOT4(mC, 8, 40)  DOT4(mC, 12, 44)
    DOT4(mD, 0, 48) DOT4(mD, 4, 52) DOT4(mD, 8, 56)  DOT4(mD, 12, 60)
#undef DOT4
    float dp = (dx + dy) + (dz + dw);
    dp = fold32_add(dp);                   // full row-dot in every lane (VALU)
    // softmax with lazy offset; den via DPP ror-reduce + one xor16 swizzle
    float e = __expf(dp - moff);
    float s16 = dppror_add(dppror_add(dppror_add(dppror_add(e, 1), 2), 4), 8);
    float den = s16 + swz16(s16);
    float ew = e / den;
    float x16 = dppror_max(dppror_max(dppror_max(dppror_max(dp, 1), 2), 4), 8);
    // update: mem += ew*(gv - ev*mem)
    const float* evp = &sbuf[cur][128 + h * 64];
    const float* gvp = &sbuf[cur][256 + h * 64];
    float4 e4, g4;
#define UPD4(V, J0, OFS) \
    e4 = *(const float4*)(evp + (OFS)); g4 = *(const float4*)(gvp + (OFS)); \
    V[(J0)+0] = fmaf(ew, fmaf(-e4.x, V[(J0)+0], g4.x), V[(J0)+0]); \
    V[(J0)+1] = fmaf(ew, fmaf(-e4.y, V[(J0)+1], g4.y), V[(J0)+1]); \
    V[(J0)+2] = fmaf(ew, fmaf(-e4.z, V[(J0)+2], g4.z), V[(J0)+2]); \
    V[(J0)+3] = fmaf(ew, fmaf(-e4.w, V[(J0)+3], g4.w), V[(J0)+3]);
    UPD4(mA, 0, 0)  UPD4(mA, 4, 4)  UPD4(mA, 8, 8)   UPD4(mA, 12, 12)
    UPD4(mB, 0, 16) UPD4(mB, 4, 20) UPD4(mB, 8, 24)  UPD4(mB, 12, 28)
    UPD4(mC, 0, 32) UPD4(mC, 4, 36) UPD4(mC, 8, 40)  UPD4(mC, 12, 44)
    UPD4(mD, 0, 48) UPD4(mD, 4, 52) UPD4(mD, 8, 56)  UPD4(mD, 12, 60)
#undef UPD4
    // stage t+1 into the other LDS buffer
    if (t < 511) {
      *(float4*)(&sbuf[nxt][4 * l]) = ga;
      *(float2*)(&sbuf[nxt][256 + 2 * l]) = gc;
    }
    // emit ew (the only recurrence output; snapshots replayed by k_snap)
    if (l < 32) ewp[(size_t)t * 32] = ew;
    moff = fmaxf(x16, swz16(x16));
  }
}

// ---------------------------------------------------------------------------
// k_snap: parallel elementwise replay of the mem recurrence. Thread = (b,m,d2)
// chain; identical fmaf order as k_memrec -> bitwise-identical snapshots.
// grid = 16 batches * 8 blocks, 256 thr; writes bf16-packed mem_all.
__global__ __launch_bounds__(256, 1) void k_snap(const float* __restrict__ st, const float* __restrict__ ew_all,
    const ushort* __restrict__ mem0, uint* __restrict__ mem_all)
{
  int b = blockIdx.x >> 3;
  int j = ((blockIdx.x & 7) << 8) + threadIdx.x;   // 0..2047
  int m = j >> 6, d2 = j & 63;
  uint u0 = ((const uint*)mem0)[(m << 6) + d2];
  float s0 = bl(u0), s1 = bh(u0);
  const float* ep = st + (size_t)b * 512 * 384 + 128 + 2 * d2;
  const float* gp = ep + 128;
  const float* ap = ew_all + (size_t)b * 512 * 32 + m;
  uint* mb = mem_all + (size_t)b * 512 * 2048 + (m << 6) + d2;
  for (int t = 0; t < 512; t += 4) {
    float2 eA = *(const float2*)(ep + (size_t)(t + 0) * 384);
    float2 eB = *(const float2*)(ep + (size_t)(t + 1) * 384);
    float2 eC = *(const float2*)(ep + (size_t)(t + 2) * 384);
    float2 eD = *(const float2*)(ep + (size_t)(t + 3) * 384);
    float2 gA = *(const float2*)(gp + (size_t)(t + 0) * 384);
    float2 gB = *(const float2*)(gp + (size_t)(t + 1) * 384);
    float2 gC = *(const float2*)(gp + (size_t)(t + 2) * 384);
    float2 gD = *(const float2*)(gp + (size_t)(t + 3) * 384);
    float a0 = ap[(size_t)(t + 0) * 32];
    float a1 = ap[(size_t)(t + 1) * 32];
    float a2 = ap[(size_t)(t + 2) * 32];
    float a3 = ap[(size_t)(t + 3) * 32];
    mb[(size_t)(t + 0) * 2048] = cvtpk(s0, s1);
    s0 = fmaf(a0, fmaf(-eA.x, s0, gA.x), s0);
    s1 = fmaf(a0, fmaf(-eA.y, s1, gA.y), s1);
    mb[(size_t)(t + 1) * 2048] = cvtpk(s0, s1);
    s0 = fmaf(a1, fmaf(-eB.x, s0, gB.x), s0);
    s1 = fmaf(a1, fmaf(-eB.y, s1, gB.y), s1);
    mb[(size_t)(t + 2) * 2048] = cvtpk(s0, s1);
    s0 = fmaf(a2, fmaf(-eC.x, s0, gC.x), s0);
    s1 = fmaf(a2, fmaf(-eC.y, s1, gC.y), s1);
    mb[(size_t)(t + 3) * 2048] = cvtpk(s0, s1);
    s0 = fmaf(a3, fmaf(-eD.x, s0, gD.x), s0);
    s1 = fmaf(a3, fmaf(-eD.y, s1, gD.y), s1);
  }
}

// ---------------------------------------------------------------------------
__global__ __launch_bounds__(256, 1) void k_read(const ushort* __restrict__ Wqkv, const ushort* __restrict__ bwo,
    const uint* __restrict__ wo_pk, const uint* __restrict__ mem_all, const float* __restrict__ q_all,
    const float* __restrict__ rg_all, const float* __restrict__ h_all, float* __restrict__ wm_all)
{
  __shared__ float Kl[32 * 133];
  __shared__ float Vl[32 * 133];
  __shared__ __align__(16) char ml[8192];
  __shared__ float ql[128];
  __shared__ float ol[128];
  __shared__ float part[256];
  int tid = threadIdx.x, l = tid & 63, w = tid >> 6;
  int b = blockIdx.x >> 6, c = blockIdx.x & 63;
  int mat = w >> 1, chh = w & 1;
  bf16x8 bfr[4][4];
#pragma unroll
  for (int ct = 0; ct < 4; ++ct)
#pragma unroll
    for (int kt = 0; kt < 4; ++kt) {
      int j = chh * 64 + ct * 16 + (l & 15);
      bfr[ct][kt] = *(const bf16x8*)(Wqkv + (size_t)(128 + mat * 128 + j) * 128 + kt * 32 + (l >> 4) * 8);
    }
  for (int s8 = 0; s8 < 8; ++s8) {
    int t = c * 8 + s8;
    size_t bt = (size_t)b * 512 + t;
    {
      const uint4* src = (const uint4*)(mem_all + bt * 2048);
      uint4 v0 = src[tid * 2], v1 = src[tid * 2 + 1];
      int row = tid >> 3;
      int b0 = row * 256 + (tid & 7) * 32;
      int sw = (row & 7) << 4;
      *(uint4*)(ml + (b0 ^ sw)) = v0;
      *(uint4*)(ml + ((b0 + 16) ^ sw)) = v1;
    }
    if (tid < 128) ql[tid] = q_all[bt * 128 + tid];
    __syncthreads();
    f32x4 acc[2][4];
#pragma unroll
    for (int rt = 0; rt < 2; ++rt)
#pragma unroll
      for (int ct = 0; ct < 4; ++ct) { f32x4 z = {0.f, 0.f, 0.f, 0.f}; acc[rt][ct] = z; }
    bf16x8 af[2][4];
#pragma unroll
    for (int rt = 0; rt < 2; ++rt)
#pragma unroll
      for (int kt = 0; kt < 4; ++kt) {
        int row = rt * 16 + (l & 15);
        int byte0 = (row * 256 + kt * 64 + (l >> 4) * 16) ^ ((row & 7) << 4);
        af[rt][kt] = *(const bf16x8*)(ml + byte0);
      }
#pragma unroll
    for (int rt = 0; rt < 2; ++rt)
#pragma unroll
      for (int ct = 0; ct < 4; ++ct)
#pragma unroll
        for (int kt = 0; kt < 4; ++kt)
          acc[rt][ct] = __builtin_amdgcn_mfma_f32_16x16x32_bf16(af[rt][kt], bfr[ct][kt], acc[rt][ct], 0, 0, 0);
    {
      float* dst = mat ? Vl : Kl;
#pragma unroll
      for (int rt = 0; rt < 2; ++rt)
#pragma unroll
        for (int ct = 0; ct < 4; ++ct)
#pragma unroll
          for (int rr = 0; rr < 4; ++rr) {
            int row = rt * 16 + (l >> 4) * 4 + rr;
            int col = chh * 64 + ct * 16 + (l & 15);
            dst[row * 133 + col] = acc[rt][ct][rr];
          }
    }
    __syncthreads();
    {
      int hh = w;
      float qv[16];
#pragma unroll
      for (int q = 0; q < 4; ++q) { F4LD(qv, 4 * q, ql + hh * 32 + (l >> 5) * 16 + 4 * q); }
      int m = l & 31;
      float sv = 0.f;
#pragma unroll
      for (int i = 0; i < 16; ++i) sv += qv[i] * Kl[m * 133 + hh * 32 + (l >> 5) * 16 + i];
      sv += __shfl_xor(sv, 32, 64);
      sv *= 0.1767766952966369f;
      float mx = sv;
      mx = fmaxf(mx, __shfl_xor(mx, 1, 64)); mx = fmaxf(mx, __shfl_xor(mx, 2, 64));
      mx = fmaxf(mx, __shfl_xor(mx, 4, 64)); mx = fmaxf(mx, __shfl_xor(mx, 8, 64));
      mx = fmaxf(mx, __shfl_xor(mx, 16, 64));
      float e = __expf(sv - mx);
      float den = e;
      den += __shfl_xor(den, 1, 64); den += __shfl_xor(den, 2, 64); den += __shfl_xor(den, 4, 64);
      den += __shfl_xor(den, 8, 64); den += __shfl_xor(den, 16, 64);
      float a = e / den;
      float o = 0.f;
      int dpos = l & 31, mh = l >> 5;
#pragma unroll
      for (int i = 0; i < 16; ++i) {
        int mm = mh * 16 + i;
        float am = __shfl(a, mm, 64);
        o += am * Vl[mm * 133 + hh * 32 + dpos];
      }
      o += __shfl_xor(o, 32, 64);
      if (l < 32) ol[hh * 32 + dpos] = o;
    }
    __syncthreads();
    {
      int j = tid & 127, dh = tid >> 7;
      float o0 = ol[l], o1 = ol[64 + l];
      float pa = 0.f;
#pragma unroll
      for (int i2 = 0; i2 < 32; ++i2) {
        int d2 = dh * 32 + i2;
        float s0, s1;
        if (dh == 0) { s0 = rdl(o0, 2 * i2); s1 = rdl(o0, 2 * i2 + 1); }
        else { s0 = rdl(o1, 2 * i2); s1 = rdl(o1, 2 * i2 + 1); }
        uint u = wo_pk[d2 * 128 + j];
        pa += s0 * bl(u) + s1 * bh(u);
      }
      part[tid] = pa;
    }
    __syncthreads();
    if (tid < 128) {
      float ro = part[tid] + part[tid + 128] + b2f(bwo[tid]);
      float rg = rg_all[bt];
      wm_all[bt * 128 + tid] = h_all[bt * 128 + tid] + rg * ro;
    }
    __syncthreads();
  }
}

// ---------------------------------------------------------------------------
__global__ __launch_bounds__(256, 1) void k_caqkv(const float* __restrict__ wm, const uint* __restrict__ pk,
    const ushort* __restrict__ bqkv, float* __restrict__ qca, float* __restrict__ kca, float* __restrict__ vca)
{
  __shared__ uint lds[8192];
  int tid = threadIdx.x;
  int wv = tid >> 6, l = tid & 63;
  for (int s = 0; s < 3; ++s) {
    __syncthreads();
    for (int i = tid; i < 8192; i += 256) { int d2 = i >> 7, j = i & 127; lds[i] = pk[d2 * 384 + s * 128 + j]; }
    __syncthreads();
    for (int ps = 0; ps < 8; ++ps) {
      int tok = blockIdx.x * 32 + ps * 4 + wv;
      int b = tok >> 9, ss = tok & 511;
      float h0 = wm[(size_t)tok * 128 + l], h1 = wm[(size_t)tok * 128 + 64 + l];
      float a0 = b2f(bqkv[s * 128 + l]), a1 = b2f(bqkv[s * 128 + 64 + l]);
#pragma unroll
      for (int d2 = 0; d2 < 64; ++d2) {
        float s0 = rdl(d2 < 32 ? h0 : h1, (2 * d2) & 63);
        float s1 = rdl(d2 < 32 ? h0 : h1, (2 * d2 + 1) & 63);
        uint u0 = lds[d2 * 128 + l], u1 = lds[d2 * 128 + 64 + l];
        a0 += s0 * bl(u0) + s1 * bh(u0);
        a1 += s0 * bl(u1) + s1 * bh(u1);
      }
#pragma unroll
      for (int k = 0; k < 2; ++k) {
        int j = l + 64 * k;
        int hd = j >> 4, dd = j & 15;
        size_t idx = ((size_t)(b * 8 + hd) * 512 + ss) * 16 + dd;
        float v = k == 0 ? a0 : a1;
        if (s == 0) qca[idx] = v * 0.25f;
        else if (s == 1) kca[idx] = v;
        else vca[idx] = v;
      }
    }
  }
}

// ---------------------------------------------------------------------------
__global__ __launch_bounds__(256, 1) void k_caattn(const float* __restrict__ qca, const float* __restrict__ kca,
    const float* __restrict__ vca, float* __restrict__ ao)
{
  __shared__ float kl[8192];       // K f32
  __shared__ uint vl[4096];        // V packed bf16 pairs
  int tid = threadIdx.x;
  int bh_ = blockIdx.x >> 1, half = blockIdx.x & 1;
  for (int i = tid; i < 8192; i += 256) kl[i] = kca[(size_t)bh_ * 8192 + i];
  for (int i = tid; i < 4096; i += 256) {
    float v0 = vca[(size_t)bh_ * 8192 + 2 * i], v1 = vca[(size_t)bh_ * 8192 + 2 * i + 1];
    vl[i] = (uint)f2b(v0) | ((uint)f2b(v1) << 16);
  }
  __syncthreads();
  int r = half * 256 + tid;
  float qv[16];
#pragma unroll
  for (int q = 0; q < 4; ++q) { F4LD(qv, 4 * q, qca + (size_t)bh_ * 8192 + r * 16 + 4 * q); }
  float o[16];
#pragma unroll
  for (int i = 0; i < 16; ++i) o[i] = 0.f;
  float mx = -3e38f, den = 0.f;
  for (int ch = 0; ch < 8; ++ch) {
    float sc[64];
#pragma unroll
    for (int m2 = 0; m2 < 64; ++m2) {
      const float* kr = kl + (ch * 64 + m2) * 16;
      float s = 0.f;
#pragma unroll
      for (int i = 0; i < 16; ++i) s += qv[i] * kr[i];
      sc[m2] = s;
    }
    float cm = sc[0];
#pragma unroll
    for (int m2 = 1; m2 < 64; ++m2) cm = fmaxf(cm, sc[m2]);
    if (cm > mx) {
      float rs = __expf(mx - cm);
      den *= rs;
#pragma unroll
      for (int i = 0; i < 16; ++i) o[i] *= rs;
      mx = cm;
    }
#pragma unroll
    for (int m2 = 0; m2 < 64; ++m2) {
      float e = __expf(sc[m2] - mx);
      den += e;
      const uint* vr = vl + (ch * 64 + m2) * 8;
#pragma unroll
      for (int i = 0; i < 8; ++i) {
        uint u = vr[i];
        o[2 * i] += e * bl(u);
        o[2 * i + 1] += e * bh(u);
      }
    }
  }
  float rd = 1.f / den;
#pragma unroll
  for (int q = 0; q < 4; ++q) {
    float4 f = make_float4(o[4 * q] * rd, o[4 * q + 1] * rd, o[4 * q + 2] * rd, o[4 * q + 3] * rd);
    *(float4*)(ao + (size_t)bh_ * 8192 + r * 16 + 4 * q) = f;
  }
}

// ---------------------------------------------------------------------------
__global__ __launch_bounds__(256, 1) void k_cafinal(const float* __restrict__ wm, const float* __restrict__ ao,
    const uint* __restrict__ pko, const uint* __restrict__ pkout,
    const ushort* __restrict__ wai, const ushort* __restrict__ bai, const ushort* __restrict__ gca,
    const ushort* __restrict__ beca, const ushort* __restrict__ boca, const ushort* __restrict__ bout,
    float* __restrict__ out)
{
  __shared__ uint lds[12288];
  __shared__ float fb[576];
  int tid = threadIdx.x;
  for (int i = tid; i < 8192; i += 256) lds[i] = pko[i];
  for (int i = tid; i < 4096; i += 256) lds[8192 + i] = pkout[i];
  for (int i = tid; i < 576; i += 256) {
    float v;
    if (i < 128) v = b2f(wai[i]);
    else if (i < 256) v = b2f(gca[i - 128]);
    else if (i < 384) v = b2f(beca[i - 256]);
    else if (i < 512) v = b2f(boca[i - 384]);
    else v = b2f(bout[i - 512]);
    fb[i] = v;
  }
  __syncthreads();
  float baiv = b2f(bai[0]);
  int wv = tid >> 6, l = tid & 63;
  for (int ps = 0; ps < 8; ++ps) {
    int tok = blockIdx.x * 32 + ps * 4 + wv;
    int b = tok >> 9, s = tok & 511;
    float w0 = wm[(size_t)tok * 128 + l], w1 = wm[(size_t)tok * 128 + 64 + l];
    float o0 = ao[((size_t)(b * 8 + (l >> 4)) * 512 + s) * 16 + (l & 15)];
    float o1 = ao[((size_t)(b * 8 + 4 + (l >> 4)) * 512 + s) * 16 + (l & 15)];
    float ip = w0 * fb[l] + w1 * fb[64 + l];
#pragma unroll
    for (int d = 1; d < 64; d <<= 1) ip += __shfl_xor(ip, d, 64);
    float it = sigm(ip + baiv);
    float a0 = fb[384 + l], a1 = fb[384 + 64 + l];
#pragma unroll
    for (int d2 = 0; d2 < 64; ++d2) {
      float s0 = rdl(d2 < 32 ? o0 : o1, (2 * d2) & 63);
      float s1 = rdl(d2 < 32 ? o0 : o1, (2 * d2 + 1) & 63);
      uint u0 = lds[d2 * 128 + l], u1 = lds[d2 * 128 + 64 + l];
      a0 += s0 * bl(u0) + s1 * bh(u0);
      a1 += s0 * bl(u1) + s1 * bh(u1);
    }
    float x0 = a0 * it + w0, x1 = a1 * it + w1;
    float smv = x0 + x1, sq = x0 * x0 + x1 * x1;
#pragma unroll
    for (int d = 1; d < 64; d <<= 1) { smv += __shfl_xor(smv, d, 64); sq += __shfl_xor(sq, d, 64); }
    float mn = smv * 0.0078125f;
    float var = sq * 0.0078125f - mn * mn;
    float rstd = rsqrtf(var + 1e-5f);
    float c0 = (x0 - mn) * rstd * fb[128 + l] + fb[256 + l];
    float c1 = (x1 - mn) * rstd * fb[128 + 64 + l] + fb[256 + 64 + l];
    float ob = fb[512 + l];
#pragma unroll
    for (int d2 = 0; d2 < 64; ++d2) {
      float s0 = rdl(d2 < 32 ? c0 : c1, (2 * d2) & 63);
      float s1 = rdl(d2 < 32 ? c0 : c1, (2 * d2 + 1) & 63);
      uint u = lds[8192 + d2 * 64 + l];
      ob += s0 * bl(u) + s1 * bh(u);
    }
    out[(size_t)tok * 64 + l] = ob;   // f32 output (reference output dtype)
  }
}

// ---------------------------------------------------------------------------
extern "C" void kernel_launch(void* const* d_in, const int* in_sizes, int n_in,
                              void* d_out, int out_size, void* d_ws, size_t ws_size,
                              hipStream_t stream)
{
  (void)out_size; (void)ws_size;
  float* ws = (float*)d_ws;
  uint* wsu = (uint*)d_ws;
  ushort* cb = (ushort*)(wsu + O_CAN);

  // canonical bf16 copies of all inputs (16B-aligned offsets)
  uint off[36]; uint cum = 0;
  for (int i = 0; i < 36; ++i) { off[i] = cum; cum = (cum + (uint)in_sizes[i] + 7u) & ~7u; }

  CVA ca;
  for (int i = 0; i < 36; ++i) ca.d[i] = CV{ d_in[i], off[i], (uint)in_sizes[i] };
  k_cvt<<<dim3(36, 16), 256, 0, stream>>>(ca, cb);

  const ushort* x        = cb + off[0];
  const ushort* W_in     = cb + off[1];
  const ushort* b_in     = cb + off[2];
  const ushort* W_l      = cb + off[3];
  const ushort* b_l      = cb + off[4];
  const ushort* g_l      = cb + off[5];
  const ushort* be_l     = cb + off[6];
  const ushort* W_ih     = cb + off[7];
  const ushort* W_hh     = cb + off[8];
  const ushort* b_ih     = cb + off[9];
  const ushort* b_hh     = cb + off[10];
  const ushort* mem0     = cb + off[11];
  const ushort* W_rh     = cb + off[12];
  const ushort* b_rh     = cb + off[13];
  const ushort* W_wh     = cb + off[14];
  const ushort* b_wh     = cb + off[15];
  const ushort* W_eh     = cb + off[16];
  const ushort* b_eh     = cb + off[17];
  const ushort* W_rg     = cb + off[18];
  const ushort* b_rg     = cb + off[19];
  const ushort* W_wg     = cb + off[20];
  const ushort* b_wg     = cb + off[21];
  const ushort* W_wm_qkv = cb + off[22];
  const ushort* b_wm_qkv = cb + off[23];
  const ushort* W_wm_o   = cb + off[24];
  const ushort* b_wm_o   = cb + off[25];
  const ushort* W_ca_qkv = cb + off[26];
  const ushort* b_ca_qkv = cb + off[27];
  const ushort* W_ca_o   = cb + off[28];
  const ushort* b_ca_o   = cb + off[29];
  const ushort* W_ai     = cb + off[30];
  const ushort* b_ai     = cb + off[31];
  const ushort* g_ca     = cb + off[32];
  const ushort* be_ca    = cb + off[33];
  const ushort* W_out    = cb + off[34];
  const ushort* b_out    = cb + off[35];

  k_wqcomb<<<64, 256, 0, stream>>>(W_wm_qkv, W_rh, b_rh, b_wm_qkv, (ushort*)(wsu + O_WQC16), ws + O_BQC);

  PA pa;
  pa.d[0]  = PD{ W_in,                       wsu + O_PWIN,  128, 32, 128, 0 };
  pa.d[1]  = PD{ W_l,                        wsu + O_PWL,   128, 64, 128, 0 };
  pa.d[2]  = PD{ W_l + 16384,                wsu + O_PWL + 8192,  128, 64, 128, 0 };
  pa.d[3]  = PD{ W_l + 32768,                wsu + O_PWL + 16384, 128, 64, 128, 0 };
  pa.d[4]  = PD{ W_ih,                       wsu + O_PWIH,  512, 64, 512, 0 };
  pa.d[5]  = PD{ W_wh,                       wsu + O_PCMB,  256, 64, 512, 0 };
  pa.d[6]  = PD{ W_eh,                       wsu + O_PCMB,  128, 64, 512, 256 };
  pa.d[7]  = PD{ (const ushort*)(wsu + O_WQC16), wsu + O_PCMB, 128, 64, 512, 384 };
  pa.d[8]  = PD{ W_ca_qkv,                   wsu + O_PQKV,  384, 64, 384, 0 };
  pa.d[9]  = PD{ W_ca_o,                     wsu + O_PWOC,  128, 64, 128, 0 };
  pa.d[10] = PD{ W_out,                      wsu + O_PWOUT,  64, 64,  64, 0 };
  pa.d[11] = PD{ W_wm_o,                     wsu + O_PWOWM, 128, 64, 128, 0 };
  k_pack<<<384, 256, 0, stream>>>(pa);
  k_whh<<<256, 256, 0, stream>>>(W_hh, ws + O_WHF);

  k_mlp<<<256, 256, 0, stream>>>(x, wsu + O_PWIN, b_in, b_l, g_l, be_l, ws + O_H);
  k_gates<<<256, 256, 0, stream>>>(ws + O_H, wsu + O_PWIH, b_ih, b_hh, ws + O_GX);
  k_lstm<<<16, 512, 0, stream>>>(ws + O_GX, ws + O_WHF, ws + O_HS);
  k_proj<<<256, 256, 0, stream>>>(ws + O_HS, wsu + O_PCMB, b_wh, b_eh, ws + O_BQC,
                                  W_rg, b_rg, W_wg, b_wg,
                                  ws + O_ST, ws + O_Q, ws + O_RGS);
  k_memrec<<<16, 64, 0, stream>>>(ws + O_ST, mem0, ws + O_EW);
  k_snap<<<128, 256, 0, stream>>>(ws + O_ST, ws + O_EW, mem0, wsu + O_MEMA);
  k_read<<<1024, 256, 0, stream>>>(W_wm_qkv, b_wm_o, wsu + O_PWOWM, wsu + O_MEMA,
                                   ws + O_Q, ws + O_RGS, ws + O_H, ws + O_WM);
  k_caqkv<<<256, 256, 0, stream>>>(ws + O_WM, wsu + O_PQKV, b_ca_qkv, ws + O_QCA, ws + O_KCA, ws + O_VCA);
  k_caattn<<<256, 256, 0, stream>>>(ws + O_QCA, ws + O_KCA, ws + O_VCA, ws + O_AO);
  k_cafinal<<<256, 256, 0, stream>>>(ws + O_WM, ws + O_AO, wsu + O_PWOC, wsu + O_PWOUT,
                                     W_ai, b_ai, g_ca, be_ca, b_ca_o, b_out, (float*)d_out);
}

// Round 7
// 1355.914 us; speedup vs baseline: 1.1432x; 1.0263x over previous
//
#include <hip/hip_runtime.h>
#include <hip/hip_bf16.h>

// ---------------------------------------------------------------------------
// NeuralComponent_4432406250089: B=16,S=512,DI=64,H=128,DO=64,L=3,M=32
// Round 12: k_memrec latency cuts. (1) depth-2 global prefetch (ST[t+2]
// issued at iter t, written at iter t+1) -> vmcnt stall hidden across ~2
// iterations; (2) v_permlane16_swap_b32 (VALU) replaces both ds_swizzle
// xor16 ops in softmax den/max (~120cy DS off the critical path);
// (3) fast rcp for ew=e/den (ew stored+shared with k_snap -> consistent).
// k_lstm layout-C (r11, verified) and all other kernels unchanged.
// ---------------------------------------------------------------------------

typedef short bf16x8 __attribute__((ext_vector_type(8)));
typedef float f32x4 __attribute__((ext_vector_type(4)));
typedef float f32x16 __attribute__((ext_vector_type(16)));

__device__ __forceinline__ float bl(uint u) { return __uint_as_float(u << 16); }
__device__ __forceinline__ float bh(uint u) { return __uint_as_float(u & 0xffff0000u); }
__device__ __forceinline__ float b2f(ushort u) { return __uint_as_float(((uint)u) << 16); }
__device__ __forceinline__ ushort f2b(float f) {
  uint u = __float_as_uint(f);
  u += 0x7fffu + ((u >> 16) & 1u);
  return (ushort)(u >> 16);
}
__device__ __forceinline__ uint cvtpk(float lo, float hi) {
  uint r;
  asm("v_cvt_pk_bf16_f32 %0, %1, %2" : "=v"(r) : "v"(lo), "v"(hi));
  return r;
}
__device__ __forceinline__ float rdl(float v, int lane) {
  return __int_as_float(__builtin_amdgcn_readlane(__float_as_int(v), lane));
}
__device__ __forceinline__ float sigm(float x) { return 1.0f / (1.0f + __expf(-x)); }
__device__ __forceinline__ float tanh_(float x) { float e = __expf(2.0f * x); return 1.0f - 2.0f / (e + 1.0f); }

// DPP rotate-reduce within 16-lane rows (VALU latency, not DS latency)
__device__ __forceinline__ float dppror_add(float v, const int n) {
  int s;
  switch (n) {
    case 1: s = __builtin_amdgcn_update_dpp(0, __float_as_int(v), 0x121, 0xF, 0xF, true); break;
    case 2: s = __builtin_amdgcn_update_dpp(0, __float_as_int(v), 0x122, 0xF, 0xF, true); break;
    case 4: s = __builtin_amdgcn_update_dpp(0, __float_as_int(v), 0x124, 0xF, 0xF, true); break;
    default: s = __builtin_amdgcn_update_dpp(0, __float_as_int(v), 0x128, 0xF, 0xF, true); break;
  }
  return v + __int_as_float(s);
}
__device__ __forceinline__ float dppror_max(float v, const int n) {
  int s;
  switch (n) {
    case 1: s = __builtin_amdgcn_update_dpp(0, __float_as_int(v), 0x121, 0xF, 0xF, true); break;
    case 2: s = __builtin_amdgcn_update_dpp(0, __float_as_int(v), 0x122, 0xF, 0xF, true); break;
    case 4: s = __builtin_amdgcn_update_dpp(0, __float_as_int(v), 0x124, 0xF, 0xF, true); break;
    default: s = __builtin_amdgcn_update_dpp(0, __float_as_int(v), 0x128, 0xF, 0xF, true); break;
  }
  return fmaxf(v, __int_as_float(s));
}
// combine the two 16-lane rows within each 32-half via v_permlane16_swap
// (VALU): with a=b=v, swap exchanges a.row{1,3} <-> b.row{0,2}; a+b then
// holds r0+r1 (lanes 0..31) / r2+r3 (32..63) in every lane.
__device__ __forceinline__ float swap16_add(float v) {
  int a = __float_as_int(v), b = a;
  asm("v_permlane16_swap_b32 %0, %1" : "+v"(a), "+v"(b));
  return __int_as_float(a) + __int_as_float(b);
}
__device__ __forceinline__ float swap16_max(float v) {
  int a = __float_as_int(v), b = a;
  asm("v_permlane16_swap_b32 %0, %1" : "+v"(a), "+v"(b));
  return fmaxf(__int_as_float(a), __int_as_float(b));
}
// full-row fold: every lane gets v[l&31] + v[32+(l&31)] (VALU permlane swap)
__device__ __forceinline__ float fold32_add(float v) {
  int a = __float_as_int(v), b = a;
  asm("v_permlane32_swap_b32 %0, %1" : "+v"(a), "+v"(b));
  return __int_as_float(a) + __int_as_float(b);
}
// quad_perm xor within 4-lane groups (VALU): ctrl 0xB1 = lane^1, 0x4E = lane^2
__device__ __forceinline__ float qx1(float v) {
  return __int_as_float(__builtin_amdgcn_update_dpp(0, __float_as_int(v), 0xB1, 0xF, 0xF, true));
}
__device__ __forceinline__ float qx2(float v) {
  return __int_as_float(__builtin_amdgcn_update_dpp(0, __float_as_int(v), 0x4E, 0xF, 0xF, true));
}

// ---- workspace offsets (in 4-byte units) ----
#define O_H     ((size_t)0)
#define O_GX    ((size_t)1048576)
#define O_EW    ((size_t)1048576)   // reuse of GX after k_lstm (memrec ew out)
#define O_QCA   ((size_t)1048576)   // reuse after k_snap/k_read
#define O_KCA   ((size_t)2097152)
#define O_VCA   ((size_t)3145728)
#define O_AO    ((size_t)4194304)
#define O_WHF   ((size_t)4194304)   // f32 W_hh (64K f32); dead before k_caattn writes AO
#define O_HS    ((size_t)5242880)
#define O_WM    ((size_t)5242880)   // reuse of HS after k_proj
#define O_ST    ((size_t)6291456)   // fused memrec stream: 16*512*384 f32
#define O_Q     ((size_t)9437184)
#define O_WGS   ((size_t)10485760)
#define O_RGS   ((size_t)10493952)
#define O_BQC   ((size_t)10502144)
#define O_MEMA  ((size_t)10502272)
#define O_PWIN  ((size_t)27279488)
#define O_PWL   ((size_t)27283584)
#define O_PWIH  ((size_t)27308160)
#define O_PCMB  ((size_t)27340928)
#define O_PQKV  ((size_t)27373696)
#define O_PWOC  ((size_t)27398272)
#define O_PWOUT ((size_t)27406464)
#define O_PWOWM ((size_t)27410688)
#define O_WQC16 ((size_t)27418880)
#define O_CAN   ((size_t)27427072)  // canonical bf16 inputs start here

#define F4LD(DST, OFS, P) { float4 _f = *(const float4*)(P); DST[(OFS)]=_f.x; DST[(OFS)+1]=_f.y; DST[(OFS)+2]=_f.z; DST[(OFS)+3]=_f.w; }

// ---------------------------------------------------------------------------
// k_cvt: per-block redundant dtype detection on x, then convert this block's
// assigned input to canonical bf16. grid = dim3(36, 16).
struct CV { const void* src; uint dst; uint n; };
struct CVA { CV d[36]; };
__global__ __launch_bounds__(256) void k_cvt(CVA a, ushort* cb)
{
  __shared__ int flag;
  int tid = threadIdx.x;
  const ushort* xu = (const ushort*)a.d[0].src;
  if (tid < 64) {
    int sane = 0;
    for (int i = tid; i < 512; i += 64) {
      int e = (xu[2 * i] >> 7) & 0xFF;
      sane += (e >= 0x70 && e <= 0x8E) ? 1 : 0;
    }
#pragma unroll
    for (int d = 1; d < 64; d <<= 1) sane += __shfl_xor(sane, d, 64);
    if (tid == 0) flag = (sane > 256) ? 0 : 1;   // 0 = buffer already bf16, 1 = f32
  }
  __syncthreads();
  int isf32 = flag;
  CV c = a.d[blockIdx.x];
  ushort* dst = cb + c.dst;
  uint start = blockIdx.y * 256 + tid, stride = gridDim.y * 256;
  if (isf32) {
    const float* s = (const float*)c.src;
    for (uint j = start; j < c.n; j += stride) dst[j] = f2b(s[j]);
  } else {
    const ushort* s = (const ushort*)c.src;
    for (uint j = start; j < c.n; j += stride) dst[j] = s[j];
  }
}

// ---------------------------------------------------------------------------
__global__ __launch_bounds__(256) void k_wqcomb(const ushort* __restrict__ Wqkv, const ushort* __restrict__ Wrh,
                                                const ushort* __restrict__ brh, const ushort* __restrict__ bqkv,
                                                ushort* __restrict__ wqc, float* __restrict__ bqc)
{
  __shared__ float qr[2][128];
  int tid = threadIdx.x;
  int r = tid >> 7, e = tid & 127;
  int j = blockIdx.x * 2 + r;
  qr[r][e] = b2f(Wqkv[j * 128 + e]);
  __syncthreads();
  float acc = 0.f;
  for (int k = 0; k < 128; ++k) acc += qr[r][k] * b2f(Wrh[k * 128 + e]);
  wqc[j * 128 + e] = f2b(acc);
  if (e == 0) {
    float s = 0.f;
    for (int k = 0; k < 128; ++k) s += qr[r][k] * b2f(brh[k]);
    bqc[j] = s + b2f(bqkv[j]);
  }
}

// ---------------------------------------------------------------------------
struct PD { const ushort* src; uint* dst; int R, C2, RT, base; };
struct PA { PD d[12]; };
__global__ __launch_bounds__(256) void k_pack(PA a)
{
  int p = blockIdx.x >> 5, sl = blockIdx.x & 31;
  PD q = a.d[p];
  for (int d2 = sl; d2 < q.C2; d2 += 32)
    for (int j = threadIdx.x; j < q.R; j += 256)
      q.dst[(size_t)d2 * q.RT + q.base + j] = *(const uint*)(q.src + (size_t)j * q.C2 * 2 + d2 * 2);
}

// ---------------------------------------------------------------------------
// k_whh: unpack W_hh bf16 -> f32, per-thread-contiguous layout for k_lstm:
// whf[th*128 + g*32 + kk] = W_hh[(g*128 + c)*128 + s*32 + kk], th = c*4+s.
__global__ __launch_bounds__(256) void k_whh(const ushort* __restrict__ Whh, float* __restrict__ whf)
{
  int e = blockIdx.x * 256 + threadIdx.x;   // 0..65535
  int j = e & 127, th = e >> 7;
  int g = j >> 5, kk = j & 31, c = th >> 2, sl = th & 3;
  whf[e] = b2f(Whh[(g * 128 + c) * 128 + sl * 32 + kk]);
}

// ---------------------------------------------------------------------------
__device__ __forceinline__ void mlp_layer(float& h0, float& h1, const uint* wp, const float* bias, int li, int l)
{
  float t0 = bias[(1 + li) * 128 + l], t1 = bias[(1 + li) * 128 + 64 + l];
#pragma unroll
  for (int d2 = 0; d2 < 64; ++d2) {
    float s0 = rdl(d2 < 32 ? h0 : h1, (2 * d2) & 63);
    float s1 = rdl(d2 < 32 ? h0 : h1, (2 * d2 + 1) & 63);
    uint u0 = wp[d2 * 128 + l], u1 = wp[d2 * 128 + 64 + l];
    t0 += s0 * bl(u0) + s1 * bh(u0);
    t1 += s0 * bl(u1) + s1 * bh(u1);
  }
  t0 = fmaxf(t0, 0.f); t1 = fmaxf(t1, 0.f);
  float sm = t0 + t1, sq = t0 * t0 + t1 * t1;
#pragma unroll
  for (int d = 1; d < 64; d <<= 1) { sm += __shfl_xor(sm, d, 64); sq += __shfl_xor(sq, d, 64); }
  float mn = sm * 0.0078125f;
  float var = sq * 0.0078125f - mn * mn;
  float rstd = rsqrtf(var + 1e-5f);
  float ng0 = bias[(4 + li) * 128 + l], ng1 = bias[(4 + li) * 128 + 64 + l];
  float nb0 = bias[(7 + li) * 128 + l], nb1 = bias[(7 + li) * 128 + 64 + l];
  h0 = (t0 - mn) * rstd * ng0 + nb0 + h0;
  h1 = (t1 - mn) * rstd * ng1 + nb1 + h1;
}

__global__ __launch_bounds__(256, 1) void k_mlp(const ushort* __restrict__ x, const uint* __restrict__ pk,
    const ushort* __restrict__ b_in, const ushort* __restrict__ b_l, const ushort* __restrict__ g_l,
    const ushort* __restrict__ be_l, float* __restrict__ h_all)
{
  __shared__ uint lds[12288];
  __shared__ float bias[1280];
  int tid = threadIdx.x;
  for (int i = tid; i < 12288; i += 256) lds[i] = pk[i];         // W_in (4096) + L0 (8192)
  for (int i = tid; i < 1280; i += 256) {
    int which = i >> 7, e = i & 127;
    float v;
    if (which == 0) v = b2f(b_in[e]);
    else if (which < 4) v = b2f(b_l[(which - 1) * 128 + e]);
    else if (which < 7) v = b2f(g_l[(which - 4) * 128 + e]);
    else v = b2f(be_l[(which - 7) * 128 + e]);
    bias[i] = v;
  }
  __syncthreads();
  int wv = tid >> 6, l = tid & 63;
  float h0a[8], h1a[8];
#pragma unroll
  for (int ps = 0; ps < 8; ++ps) {
    int tok = blockIdx.x * 32 + ps * 4 + wv;
    float xv = b2f(x[(size_t)tok * 64 + l]);
    float h0 = bias[l], h1 = bias[64 + l];
#pragma unroll
    for (int d2 = 0; d2 < 32; ++d2) {
      float s0 = rdl(xv, 2 * d2), s1 = rdl(xv, 2 * d2 + 1);
      uint u0 = lds[d2 * 128 + l], u1 = lds[d2 * 128 + 64 + l];
      h0 += s0 * bl(u0) + s1 * bh(u0);
      h1 += s0 * bl(u1) + s1 * bh(u1);
    }
    mlp_layer(h0, h1, lds + 4096, bias, 0, l);
    h0a[ps] = h0; h1a[ps] = h1;
  }
  __syncthreads();
  for (int i = tid; i < 8192; i += 256) lds[i] = pk[12288 + i];  // L1
  __syncthreads();
#pragma unroll
  for (int ps = 0; ps < 8; ++ps) {
    float h0 = h0a[ps], h1 = h1a[ps];
    mlp_layer(h0, h1, lds, bias, 1, l);
    h0a[ps] = h0; h1a[ps] = h1;
  }
  __syncthreads();
  for (int i = tid; i < 8192; i += 256) lds[i] = pk[20480 + i];  // L2
  __syncthreads();
#pragma unroll
  for (int ps = 0; ps < 8; ++ps) {
    int tok = blockIdx.x * 32 + ps * 4 + wv;
    float h0 = h0a[ps], h1 = h1a[ps];
    mlp_layer(h0, h1, lds, bias, 2, l);
    h_all[(size_t)tok * 128 + l] = h0;
    h_all[(size_t)tok * 128 + 64 + l] = h1;
  }
}

// ---------------------------------------------------------------------------
__global__ __launch_bounds__(256, 1) void k_gates(const float* __restrict__ h_all, const uint* __restrict__ pk,
    const ushort* __restrict__ b_ih, const ushort* __restrict__ b_hh, float* __restrict__ gx)
{
  __shared__ uint lds[8192];
  __shared__ float biasg[512];
  int tid = threadIdx.x;
  for (int i = tid; i < 512; i += 256) biasg[i] = b2f(b_ih[i]) + b2f(b_hh[i]);
  int wv = tid >> 6, l = tid & 63;
  for (int s = 0; s < 4; ++s) {
    __syncthreads();
    for (int i = tid; i < 8192; i += 256) { int d2 = i >> 7, j = i & 127; lds[i] = pk[d2 * 512 + s * 128 + j]; }
    __syncthreads();
    for (int ps = 0; ps < 8; ++ps) {
      int tok = blockIdx.x * 32 + ps * 4 + wv;
      float h0 = h_all[(size_t)tok * 128 + l], h1 = h_all[(size_t)tok * 128 + 64 + l];
      float a0 = biasg[s * 128 + l], a1 = biasg[s * 128 + 64 + l];
#pragma unroll
      for (int d2 = 0; d2 < 64; ++d2) {
        float s0 = rdl(d2 < 32 ? h0 : h1, (2 * d2) & 63);
        float s1 = rdl(d2 < 32 ? h0 : h1, (2 * d2 + 1) & 63);
        uint u0 = lds[d2 * 128 + l], u1 = lds[d2 * 128 + 64 + l];
        a0 += s0 * bl(u0) + s1 * bh(u0);
        a1 += s0 * bl(u1) + s1 * bh(u1);
      }
      gx[(size_t)tok * 512 + s * 128 + l] = a0;
      gx[(size_t)tok * 512 + s * 128 + 64 + l] = a1;
    }
  }
}

// ---------------------------------------------------------------------------
// k_lstm layout-C (r11, verified): tid = c*4+s; thread partial-dots all 4
// gates of cell c over hs[32s..32s+32); DPP quad_perm slice-reduce; redundant
// cs update; ping-pong hsl -> ONE barrier/step. Weights f32 from k_whh.
__global__ __launch_bounds__(512, 2) void k_lstm(const float* __restrict__ gx, const float* __restrict__ whf,
                                                 float* __restrict__ hs_all)
{
  __shared__ __align__(16) float hsl[2][128];
  int tid = threadIdx.x;
  int b = blockIdx.x;
  int s = tid & 3, c = tid >> 2;
  f32x16 wA, wB, wC, wD, wE, wF, wG, wH;   // w[g*32+kk]: A,B=g0 C,D=g1 E,F=g2 G,H=g3
  {
    const float4* wp = (const float4*)(whf + (size_t)tid * 128);
    float4 a0, a1, a2, a3;
#define LW16(V, Q) \
    a0 = wp[(Q)]; a1 = wp[(Q) + 1]; a2 = wp[(Q) + 2]; a3 = wp[(Q) + 3]; \
    V[0]=a0.x; V[1]=a0.y; V[2]=a0.z; V[3]=a0.w; V[4]=a1.x; V[5]=a1.y; V[6]=a1.z; V[7]=a1.w; \
    V[8]=a2.x; V[9]=a2.y; V[10]=a2.z; V[11]=a2.w; V[12]=a3.x; V[13]=a3.y; V[14]=a3.z; V[15]=a3.w;
    LW16(wA, 0)  LW16(wB, 4)  LW16(wC, 8)  LW16(wD, 12)
    LW16(wE, 16) LW16(wF, 20) LW16(wG, 24) LW16(wH, 28)
#undef LW16
  }
  if (tid < 128) hsl[0][tid] = 0.f;
  float cs = 0.f;                            // private copy per lane (4x redundant)
  const float* gbase = gx + (size_t)b * 512 * 512 + s * 128 + c;
  float gcur = gbase[0];
  float* hout = hs_all + (size_t)b * 512 * 128 + c;
  __syncthreads();
  for (int t = 0; t < 512; ++t) {
    float gnext = 0.f;
    if (t < 511) gnext = gbase[(size_t)(t + 1) * 512];
    const float* hp = &hsl[t & 1][s * 32];
    float p0 = (s == 0) ? gcur : 0.f;
    float p1 = (s == 1) ? gcur : 0.f;
    float p2 = (s == 2) ? gcur : 0.f;
    float p3 = (s == 3) ? gcur : 0.f;
    float4 h4;
#define DOT4(V0, V1, V2, V3, J, HOFS) \
    h4 = *(const float4*)(hp + (HOFS)); \
    p0 = fmaf(V0[(J)+0], h4.x, p0); p0 = fmaf(V0[(J)+1], h4.y, p0); p0 = fmaf(V0[(J)+2], h4.z, p0); p0 = fmaf(V0[(J)+3], h4.w, p0); \
    p1 = fmaf(V1[(J)+0], h4.x, p1); p1 = fmaf(V1[(J)+1], h4.y, p1); p1 = fmaf(V1[(J)+2], h4.z, p1); p1 = fmaf(V1[(J)+3], h4.w, p1); \
    p2 = fmaf(V2[(J)+0], h4.x, p2); p2 = fmaf(V2[(J)+1], h4.y, p2); p2 = fmaf(V2[(J)+2], h4.z, p2); p2 = fmaf(V2[(J)+3], h4.w, p2); \
    p3 = fmaf(V3[(J)+0], h4.x, p3); p3 = fmaf(V3[(J)+1], h4.y, p3); p3 = fmaf(V3[(J)+2], h4.z, p3); p3 = fmaf(V3[(J)+3], h4.w, p3);
    DOT4(wA, wC, wE, wG, 0, 0)   DOT4(wA, wC, wE, wG, 4, 4)
    DOT4(wA, wC, wE, wG, 8, 8)   DOT4(wA, wC, wE, wG, 12, 12)
    DOT4(wB, wD, wF, wH, 0, 16)  DOT4(wB, wD, wF, wH, 4, 20)
    DOT4(wB, wD, wF, wH, 8, 24)  DOT4(wB, wD, wF, wH, 12, 28)
#undef DOT4
    // slice reduction within 4-lane group (VALU DPP, no LDS)
    p0 += qx1(p0); p0 += qx2(p0);
    p1 += qx1(p1); p1 += qx2(p1);
    p2 += qx1(p2); p2 += qx2(p2);
    p3 += qx1(p3); p3 += qx2(p3);
    // cell update (redundant across the 4 group lanes)
    cs = sigm(p1) * cs + sigm(p0) * tanh_(p2);
    float hv = sigm(p3) * tanh_(cs);
    if (s == 0) {
      hsl[(t + 1) & 1][c] = hv;
      hout[(size_t)t * 128] = hv;
    }
    gcur = gnext;
    __syncthreads();                         // hsl[(t+1)&1] ready for next step
  }
}

// ---------------------------------------------------------------------------
// k_proj: s=0 wk -> ST[0..128) + rg; s=1 wv -> gv=wg*wv -> ST[256..384);
// s=2 ev=sigm -> ST[128..256); s=3 q -> q_a. ST row = 384 f32 per (b,t).
__global__ __launch_bounds__(256, 1) void k_proj(const float* __restrict__ hs_all, const uint* __restrict__ pk,
    const ushort* __restrict__ bwh, const ushort* __restrict__ beh, const float* __restrict__ bqc,
    const ushort* __restrict__ wrg, const ushort* __restrict__ brg, const ushort* __restrict__ wwg,
    const ushort* __restrict__ bwg,
    float* __restrict__ st, float* __restrict__ q_a, float* __restrict__ rg_a)
{
  __shared__ uint lds[8192];
  __shared__ float biasc[512];
  int tid = threadIdx.x;
  for (int i = tid; i < 512; i += 256)
    biasc[i] = (i < 256) ? b2f(bwh[i]) : (i < 384) ? b2f(beh[i - 256]) : bqc[i - 384];
  float brgv = b2f(brg[0]), bwgv = b2f(bwg[0]);
  int wv = tid >> 6, l = tid & 63;
  for (int s = 0; s < 4; ++s) {
    __syncthreads();
    for (int i = tid; i < 8192; i += 256) { int d2 = i >> 7, j = i & 127; lds[i] = pk[d2 * 512 + s * 128 + j]; }
    __syncthreads();
    for (int ps = 0; ps < 8; ++ps) {
      int tok = blockIdx.x * 32 + ps * 4 + wv;
      float h0 = hs_all[(size_t)tok * 128 + l], h1 = hs_all[(size_t)tok * 128 + 64 + l];
      float a0 = biasc[s * 128 + l], a1 = biasc[s * 128 + 64 + l];
#pragma unroll
      for (int d2 = 0; d2 < 64; ++d2) {
        float s0 = rdl(d2 < 32 ? h0 : h1, (2 * d2) & 63);
        float s1 = rdl(d2 < 32 ? h0 : h1, (2 * d2 + 1) & 63);
        uint u0 = lds[d2 * 128 + l], u1 = lds[d2 * 128 + 64 + l];
        a0 += s0 * bl(u0) + s1 * bh(u0);
        a1 += s0 * bl(u1) + s1 * bh(u1);
      }
      if (s == 0) {
        st[(size_t)tok * 384 + l] = a0;
        st[(size_t)tok * 384 + 64 + l] = a1;
        float pr = h0 * b2f(wrg[l]) + h1 * b2f(wrg[64 + l]);
#pragma unroll
        for (int d = 1; d < 64; d <<= 1) pr += __shfl_xor(pr, d, 64);
        if (l == 0) rg_a[tok] = sigm(pr + brgv);
      } else if (s == 1) {
        float pw = h0 * b2f(wwg[l]) + h1 * b2f(wwg[64 + l]);
#pragma unroll
        for (int d = 1; d < 64; d <<= 1) pw += __shfl_xor(pw, d, 64);
        float wg = sigm(pw + bwgv);
        st[(size_t)tok * 384 + 256 + l] = wg * a0;
        st[(size_t)tok * 384 + 256 + 64 + l] = wg * a1;
      } else if (s == 2) {
        st[(size_t)tok * 384 + 128 + l] = sigm(a0);
        st[(size_t)tok * 384 + 128 + 64 + l] = sigm(a1);
      } else {
        q_a[(size_t)tok * 128 + l] = a0;
        q_a[(size_t)tok * 128 + 64 + l] = a1;
      }
    }
  }
}

// ---------------------------------------------------------------------------
// k_memrec: one wave per batch. Lane l: row r=l&31, half h=l>>5, mem state in
// FOUR NAMED f32x16 vectors. Dot lane-local; halves folded via permlane32.
// Softmax den/max: DPP ror + v_permlane16_swap (all VALU, no DS). Lazy exp
// offset. Depth-2 global prefetch (ST[t+2] issued at t, written at t+1).
// Outputs ONLY ew[t][m]; snapshots replayed by k_snap.
__global__ __launch_bounds__(64, 1) void k_memrec(const float* __restrict__ st, const ushort* __restrict__ mem0,
    float* __restrict__ ew_all)
{
  __shared__ __align__(16) float sbuf[2][384];
  int l = threadIdx.x;
  int b = blockIdx.x;
  int r = l & 31, h = l >> 5;
  f32x16 mA, mB, mC, mD;   // local dims 0..63 = global dims h*64 + (0..63) of row r
  {
    const uint* m0 = (const uint*)mem0 + r * 64 + 32 * h;
    uint4 uq;
#define LD16(V, OFS) \
    uq = *(const uint4*)(m0 + (OFS)); \
    V[0]=bl(uq.x); V[1]=bh(uq.x); V[2]=bl(uq.y); V[3]=bh(uq.y); \
    V[4]=bl(uq.z); V[5]=bh(uq.z); V[6]=bl(uq.w); V[7]=bh(uq.w); \
    uq = *(const uint4*)(m0 + (OFS) + 4); \
    V[8]=bl(uq.x); V[9]=bh(uq.x); V[10]=bl(uq.y); V[11]=bh(uq.y); \
    V[12]=bl(uq.z); V[13]=bh(uq.z); V[14]=bl(uq.w); V[15]=bh(uq.w);
    LD16(mA, 0) LD16(mB, 8) LD16(mC, 16) LD16(mD, 24)
#undef LD16
  }
  const float* stb = st + (size_t)b * 512 * 384;
  {
    // stage ST[0] directly; ST[1] into flight registers
    float4 a = *(const float4*)(stb + 4 * l);
    float2 c = *(const float2*)(stb + 256 + 2 * l);
    *(float4*)(&sbuf[0][4 * l]) = a;
    *(float2*)(&sbuf[0][256 + 2 * l]) = c;
  }
  float4 ga1 = *(const float4*)(stb + 384 + 4 * l);
  float2 gc1 = *(const float2*)(stb + 384 + 256 + 2 * l);
  float moff = 0.f;
  float* ewp = ew_all + (size_t)b * 512 * 32 + r;
  for (int t = 0; t < 512; ++t) {
    int cur = t & 1, nxt = cur ^ 1;
    // depth-2 prefetch: issue ST[t+2] now, consumed by the ds_write at t+1
    float4 ga2 = make_float4(0.f, 0.f, 0.f, 0.f);
    float2 gc2 = make_float2(0.f, 0.f);
    if (t + 2 < 512) {
      const float* sp = stb + (size_t)(t + 2) * 384;
      ga2 = *(const float4*)(sp + 4 * l);
      gc2 = *(const float2*)(sp + 256 + 2 * l);
    }
    // lane-local dot over this half's 64 dims (LDS broadcast reads)
    const float* wkp = &sbuf[cur][h * 64];
    float dx = 0.f, dy = 0.f, dz = 0.f, dw = 0.f;
    float4 w4;
#define DOT4(V, J0, OFS) \
    w4 = *(const float4*)(wkp + (OFS)); \
    dx = fmaf(w4.x, V[(J0)+0], dx); dy = fmaf(w4.y, V[(J0)+1], dy); \
    dz = fmaf(w4.z, V[(J0)+2], dz); dw = fmaf(w4.w, V[(J0)+3], dw);
    DOT4(mA, 0, 0)  DOT4(mA, 4, 4)  DOT4(mA, 8, 8)   DOT4(mA, 12, 12)
    DOT4(mB, 0, 16) DOT4(mB, 4, 20) DOT4(mB, 8, 24)  DOT4(mB, 12, 28)
    DOT4(mC, 0, 32) DOT4(mC, 4, 36) DOT4(mC, 8, 40)  DOT4(mC, 12, 44)
    DOT4(mD, 0, 48) DOT4(mD, 4, 52) DOT4(mD, 8, 56)  DOT4(mD, 12, 60)
#undef DOT4
    float dp = (dx + dy) + (dz + dw);
    dp = fold32_add(dp);                   // full row-dot in every lane (VALU)
    // softmax, lazy offset; den via DPP ror + permlane16 swap (all VALU)
    float e = __expf(dp - moff);
    float s16 = dppror_add(dppror_add(dppror_add(dppror_add(e, 1), 2), 4), 8);
    float den = swap16_add(s16);
    float ew = e * __builtin_amdgcn_rcpf(den);
    float x16 = dppror_max(dppror_max(dppror_max(dppror_max(dp, 1), 2), 4), 8);
    // update: mem += ew*(gv - ev*mem)
    const float* evp = &sbuf[cur][128 + h * 64];
    const float* gvp = &sbuf[cur][256 + h * 64];
    float4 e4, g4;
#define UPD4(V, J0, OFS) \
    e4 = *(const float4*)(evp + (OFS)); g4 = *(const float4*)(gvp + (OFS)); \
    V[(J0)+0] = fmaf(ew, fmaf(-e4.x, V[(J0)+0], g4.x), V[(J0)+0]); \
    V[(J0)+1] = fmaf(ew, fmaf(-e4.y, V[(J0)+1], g4.y), V[(J0)+1]); \
    V[(J0)+2] = fmaf(ew, fmaf(-e4.z, V[(J0)+2], g4.z), V[(J0)+2]); \
    V[(J0)+3] = fmaf(ew, fmaf(-e4.w, V[(J0)+3], g4.w), V[(J0)+3]);
    UPD4(mA, 0, 0)  UPD4(mA, 4, 4)  UPD4(mA, 8, 8)   UPD4(mA, 12, 12)
    UPD4(mB, 0, 16) UPD4(mB, 4, 20) UPD4(mB, 8, 24)  UPD4(mB, 12, 28)
    UPD4(mC, 0, 32) UPD4(mC, 4, 36) UPD4(mC, 8, 40)  UPD4(mC, 12, 44)
    UPD4(mD, 0, 48) UPD4(mD, 4, 52) UPD4(mD, 8, 56)  UPD4(mD, 12, 60)
#undef UPD4
    // stage ST[t+1] (loaded at iter t-1) into the other LDS buffer
    if (t < 511) {
      *(float4*)(&sbuf[nxt][4 * l]) = ga1;
      *(float2*)(&sbuf[nxt][256 + 2 * l]) = gc1;
    }
    ga1 = ga2; gc1 = gc2;
    // emit ew (the only recurrence output; snapshots replayed by k_snap)
    if (l < 32) ewp[(size_t)t * 32] = ew;
    moff = swap16_max(x16);
  }
}

// ---------------------------------------------------------------------------
// k_snap: parallel elementwise replay of the mem recurrence. Thread = (b,m,d2)
// chain; identical fmaf order as k_memrec -> bitwise-identical snapshots.
// grid = 16 batches * 8 blocks, 256 thr; writes bf16-packed mem_all.
__global__ __launch_bounds__(256, 1) void k_snap(const float* __restrict__ st, const float* __restrict__ ew_all,
    const ushort* __restrict__ mem0, uint* __restrict__ mem_all)
{
  int b = blockIdx.x >> 3;
  int j = ((blockIdx.x & 7) << 8) + threadIdx.x;   // 0..2047
  int m = j >> 6, d2 = j & 63;
  uint u0 = ((const uint*)mem0)[(m << 6) + d2];
  float s0 = bl(u0), s1 = bh(u0);
  const float* ep = st + (size_t)b * 512 * 384 + 128 + 2 * d2;
  const float* gp = ep + 128;
  const float* ap = ew_all + (size_t)b * 512 * 32 + m;
  uint* mb = mem_all + (size_t)b * 512 * 2048 + (m << 6) + d2;
  for (int t = 0; t < 512; t += 4) {
    float2 eA = *(const float2*)(ep + (size_t)(t + 0) * 384);
    float2 eB = *(const float2*)(ep + (size_t)(t + 1) * 384);
    float2 eC = *(const float2*)(ep + (size_t)(t + 2) * 384);
    float2 eD = *(const float2*)(ep + (size_t)(t + 3) * 384);
    float2 gA = *(const float2*)(gp + (size_t)(t + 0) * 384);
    float2 gB = *(const float2*)(gp + (size_t)(t + 1) * 384);
    float2 gC = *(const float2*)(gp + (size_t)(t + 2) * 384);
    float2 gD = *(const float2*)(gp + (size_t)(t + 3) * 384);
    float a0 = ap[(size_t)(t + 0) * 32];
    float a1 = ap[(size_t)(t + 1) * 32];
    float a2 = ap[(size_t)(t + 2) * 32];
    float a3 = ap[(size_t)(t + 3) * 32];
    mb[(size_t)(t + 0) * 2048] = cvtpk(s0, s1);
    s0 = fmaf(a0, fmaf(-eA.x, s0, gA.x), s0);
    s1 = fmaf(a0, fmaf(-eA.y, s1, gA.y), s1);
    mb[(size_t)(t + 1) * 2048] = cvtpk(s0, s1);
    s0 = fmaf(a1, fmaf(-eB.x, s0, gB.x), s0);
    s1 = fmaf(a1, fmaf(-eB.y, s1, gB.y), s1);
    mb[(size_t)(t + 2) * 2048] = cvtpk(s0, s1);
    s0 = fmaf(a2, fmaf(-eC.x, s0, gC.x), s0);
    s1 = fmaf(a2, fmaf(-eC.y, s1, gC.y), s1);
    mb[(size_t)(t + 3) * 2048] = cvtpk(s0, s1);
    s0 = fmaf(a3, fmaf(-eD.x, s0, gD.x), s0);
    s1 = fmaf(a3, fmaf(-eD.y, s1, gD.y), s1);
  }
}

// ---------------------------------------------------------------------------
__global__ __launch_bounds__(256, 1) void k_read(const ushort* __restrict__ Wqkv, const ushort* __restrict__ bwo,
    const uint* __restrict__ wo_pk, const uint* __restrict__ mem_all, const float* __restrict__ q_all,
    const float* __restrict__ rg_all, const float* __restrict__ h_all, float* __restrict__ wm_all)
{
  __shared__ float Kl[32 * 133];
  __shared__ float Vl[32 * 133];
  __shared__ __align__(16) char ml[8192];
  __shared__ float ql[128];
  __shared__ float ol[128];
  __shared__ float part[256];
  int tid = threadIdx.x, l = tid & 63, w = tid >> 6;
  int b = blockIdx.x >> 6, c = blockIdx.x & 63;
  int mat = w >> 1, chh = w & 1;
  bf16x8 bfr[4][4];
#pragma unroll
  for (int ct = 0; ct < 4; ++ct)
#pragma unroll
    for (int kt = 0; kt < 4; ++kt) {
      int j = chh * 64 + ct * 16 + (l & 15);
      bfr[ct][kt] = *(const bf16x8*)(Wqkv + (size_t)(128 + mat * 128 + j) * 128 + kt * 32 + (l >> 4) * 8);
    }
  for (int s8 = 0; s8 < 8; ++s8) {
    int t = c * 8 + s8;
    size_t bt = (size_t)b * 512 + t;
    {
      const uint4* src = (const uint4*)(mem_all + bt * 2048);
      uint4 v0 = src[tid * 2], v1 = src[tid * 2 + 1];
      int row = tid >> 3;
      int b0 = row * 256 + (tid & 7) * 32;
      int sw = (row & 7) << 4;
      *(uint4*)(ml + (b0 ^ sw)) = v0;
      *(uint4*)(ml + ((b0 + 16) ^ sw)) = v1;
    }
    if (tid < 128) ql[tid] = q_all[bt * 128 + tid];
    __syncthreads();
    f32x4 acc[2][4];
#pragma unroll
    for (int rt = 0; rt < 2; ++rt)
#pragma unroll
      for (int ct = 0; ct < 4; ++ct) { f32x4 z = {0.f, 0.f, 0.f, 0.f}; acc[rt][ct] = z; }
    bf16x8 af[2][4];
#pragma unroll
    for (int rt = 0; rt < 2; ++rt)
#pragma unroll
      for (int kt = 0; kt < 4; ++kt) {
        int row = rt * 16 + (l & 15);
        int byte0 = (row * 256 + kt * 64 + (l >> 4) * 16) ^ ((row & 7) << 4);
        af[rt][kt] = *(const bf16x8*)(ml + byte0);
      }
#pragma unroll
    for (int rt = 0; rt < 2; ++rt)
#pragma unroll
      for (int ct = 0; ct < 4; ++ct)
#pragma unroll
        for (int kt = 0; kt < 4; ++kt)
          acc[rt][ct] = __builtin_amdgcn_mfma_f32_16x16x32_bf16(af[rt][kt], bfr[ct][kt], acc[rt][ct], 0, 0, 0);
    {
      float* dst = mat ? Vl : Kl;
#pragma unroll
      for (int rt = 0; rt < 2; ++rt)
#pragma unroll
        for (int ct = 0; ct < 4; ++ct)
#pragma unroll
          for (int rr = 0; rr < 4; ++rr) {
            int row = rt * 16 + (l >> 4) * 4 + rr;
            int col = chh * 64 + ct * 16 + (l & 15);
            dst[row * 133 + col] = acc[rt][ct][rr];
          }
    }
    __syncthreads();
    {
      int hh = w;
      float qv[16];
#pragma unroll
      for (int q = 0; q < 4; ++q) { F4LD(qv, 4 * q, ql + hh * 32 + (l >> 5) * 16 + 4 * q); }
      int m = l & 31;
      float sv = 0.f;
#pragma unroll
      for (int i = 0; i < 16; ++i) sv += qv[i] * Kl[m * 133 + hh * 32 + (l >> 5) * 16 + i];
      sv += __shfl_xor(sv, 32, 64);
      sv *= 0.1767766952966369f;
      float mx = sv;
      mx = fmaxf(mx, __shfl_xor(mx, 1, 64)); mx = fmaxf(mx, __shfl_xor(mx, 2, 64));
      mx = fmaxf(mx, __shfl_xor(mx, 4, 64)); mx = fmaxf(mx, __shfl_xor(mx, 8, 64));
      mx = fmaxf(mx, __shfl_xor(mx, 16, 64));
      float e = __expf(sv - mx);
      float den = e;
      den += __shfl_xor(den, 1, 64); den += __shfl_xor(den, 2, 64); den += __shfl_xor(den, 4, 64);
      den += __shfl_xor(den, 8, 64); den += __shfl_xor(den, 16, 64);
      float a = e / den;
      float o = 0.f;
      int dpos = l & 31, mh = l >> 5;
#pragma unroll
      for (int i = 0; i < 16; ++i) {
        int mm = mh * 16 + i;
        float am = __shfl(a, mm, 64);
        o += am * Vl[mm * 133 + hh * 32 + dpos];
      }
      o += __shfl_xor(o, 32, 64);
      if (l < 32) ol[hh * 32 + dpos] = o;
    }
    __syncthreads();
    {
      int j = tid & 127, dh = tid >> 7;
      float o0 = ol[l], o1 = ol[64 + l];
      float pa = 0.f;
#pragma unroll
      for (int i2 = 0; i2 < 32; ++i2) {
        int d2 = dh * 32 + i2;
        float s0, s1;
        if (dh == 0) { s0 = rdl(o0, 2 * i2); s1 = rdl(o0, 2 * i2 + 1); }
        else { s0 = rdl(o1, 2 * i2); s1 = rdl(o1, 2 * i2 + 1); }
        uint u = wo_pk[d2 * 128 + j];
        pa += s0 * bl(u) + s1 * bh(u);
      }
      part[tid] = pa;
    }
    __syncthreads();
    if (tid < 128) {
      float ro = part[tid] + part[tid + 128] + b2f(bwo[tid]);
      float rg = rg_all[bt];
      wm_all[bt * 128 + tid] = h_all[bt * 128 + tid] + rg * ro;
    }
    __syncthreads();
  }
}

// ---------------------------------------------------------------------------
__global__ __launch_bounds__(256, 1) void k_caqkv(const float* __restrict__ wm, const uint* __restrict__ pk,
    const ushort* __restrict__ bqkv, float* __restrict__ qca, float* __restrict__ kca, float* __restrict__ vca)
{
  __shared__ uint lds[8192];
  int tid = threadIdx.x;
  int wv = tid >> 6, l = tid & 63;
  for (int s = 0; s < 3; ++s) {
    __syncthreads();
    for (int i = tid; i < 8192; i += 256) { int d2 = i >> 7, j = i & 127; lds[i] = pk[d2 * 384 + s * 128 + j]; }
    __syncthreads();
    for (int ps = 0; ps < 8; ++ps) {
      int tok = blockIdx.x * 32 + ps * 4 + wv;
      int b = tok >> 9, ss = tok & 511;
      float h0 = wm[(size_t)tok * 128 + l], h1 = wm[(size_t)tok * 128 + 64 + l];
      float a0 = b2f(bqkv[s * 128 + l]), a1 = b2f(bqkv[s * 128 + 64 + l]);
#pragma unroll
      for (int d2 = 0; d2 < 64; ++d2) {
        float s0 = rdl(d2 < 32 ? h0 : h1, (2 * d2) & 63);
        float s1 = rdl(d2 < 32 ? h0 : h1, (2 * d2 + 1) & 63);
        uint u0 = lds[d2 * 128 + l], u1 = lds[d2 * 128 + 64 + l];
        a0 += s0 * bl(u0) + s1 * bh(u0);
        a1 += s0 * bl(u1) + s1 * bh(u1);
      }
#pragma unroll
      for (int k = 0; k < 2; ++k) {
        int j = l + 64 * k;
        int hd = j >> 4, dd = j & 15;
        size_t idx = ((size_t)(b * 8 + hd) * 512 + ss) * 16 + dd;
        float v = k == 0 ? a0 : a1;
        if (s == 0) qca[idx] = v * 0.25f;
        else if (s == 1) kca[idx] = v;
        else vca[idx] = v;
      }
    }
  }
}

// ---------------------------------------------------------------------------
__global__ __launch_bounds__(256, 1) void k_caattn(const float* __restrict__ qca, const float* __restrict__ kca,
    const float* __restrict__ vca, float* __restrict__ ao)
{
  __shared__ float kl[8192];       // K f32
  __shared__ uint vl[4096];        // V packed bf16 pairs
  int tid = threadIdx.x;
  int bh_ = blockIdx.x >> 1, half = blockIdx.x & 1;
  for (int i = tid; i < 8192; i += 256) kl[i] = kca[(size_t)bh_ * 8192 + i];
  for (int i = tid; i < 4096; i += 256) {
    float v0 = vca[(size_t)bh_ * 8192 + 2 * i], v1 = vca[(size_t)bh_ * 8192 + 2 * i + 1];
    vl[i] = (uint)f2b(v0) | ((uint)f2b(v1) << 16);
  }
  __syncthreads();
  int r = half * 256 + tid;
  float qv[16];
#pragma unroll
  for (int q = 0; q < 4; ++q) { F4LD(qv, 4 * q, qca + (size_t)bh_ * 8192 + r * 16 + 4 * q); }
  float o[16];
#pragma unroll
  for (int i = 0; i < 16; ++i) o[i] = 0.f;
  float mx = -3e38f, den = 0.f;
  for (int ch = 0; ch < 8; ++ch) {
    float sc[64];
#pragma unroll
    for (int m2 = 0; m2 < 64; ++m2) {
      const float* kr = kl + (ch * 64 + m2) * 16;
      float s = 0.f;
#pragma unroll
      for (int i = 0; i < 16; ++i) s += qv[i] * kr[i];
      sc[m2] = s;
    }
    float cm = sc[0];
#pragma unroll
    for (int m2 = 1; m2 < 64; ++m2) cm = fmaxf(cm, sc[m2]);
    if (cm > mx) {
      float rs = __expf(mx - cm);
      den *= rs;
#pragma unroll
      for (int i = 0; i < 16; ++i) o[i] *= rs;
      mx = cm;
    }
#pragma unroll
    for (int m2 = 0; m2 < 64; ++m2) {
      float e = __expf(sc[m2] - mx);
      den += e;
      const uint* vr = vl + (ch * 64 + m2) * 8;
#pragma unroll
      for (int i = 0; i < 8; ++i) {
        uint u = vr[i];
        o[2 * i] += e * bl(u);
        o[2 * i + 1] += e * bh(u);
      }
    }
  }
  float rd = 1.f / den;
#pragma unroll
  for (int q = 0; q < 4; ++q) {
    float4 f = make_float4(o[4 * q] * rd, o[4 * q + 1] * rd, o[4 * q + 2] * rd, o[4 * q + 3] * rd);
    *(float4*)(ao + (size_t)bh_ * 8192 + r * 16 + 4 * q) = f;
  }
}

// ---------------------------------------------------------------------------
__global__ __launch_bounds__(256, 1) void k_cafinal(const float* __restrict__ wm, const float* __restrict__ ao,
    const uint* __restrict__ pko, const uint* __restrict__ pkout,
    const ushort* __restrict__ wai, const ushort* __restrict__ bai, const ushort* __restrict__ gca,
    const ushort* __restrict__ beca, const ushort* __restrict__ boca, const ushort* __restrict__ bout,
    float* __restrict__ out)
{
  __shared__ uint lds[12288];
  __shared__ float fb[576];
  int tid = threadIdx.x;
  for (int i = tid; i < 8192; i += 256) lds[i] = pko[i];
  for (int i = tid; i < 4096; i += 256) lds[8192 + i] = pkout[i];
  for (int i = tid; i < 576; i += 256) {
    float v;
    if (i < 128) v = b2f(wai[i]);
    else if (i < 256) v = b2f(gca[i - 128]);
    else if (i < 384) v = b2f(beca[i - 256]);
    else if (i < 512) v = b2f(boca[i - 384]);
    else v = b2f(bout[i - 512]);
    fb[i] = v;
  }
  __syncthreads();
  float baiv = b2f(bai[0]);
  int wv = tid >> 6, l = tid & 63;
  for (int ps = 0; ps < 8; ++ps) {
    int tok = blockIdx.x * 32 + ps * 4 + wv;
    int b = tok >> 9, s = tok & 511;
    float w0 = wm[(size_t)tok * 128 + l], w1 = wm[(size_t)tok * 128 + 64 + l];
    float o0 = ao[((size_t)(b * 8 + (l >> 4)) * 512 + s) * 16 + (l & 15)];
    float o1 = ao[((size_t)(b * 8 + 4 + (l >> 4)) * 512 + s) * 16 + (l & 15)];
    float ip = w0 * fb[l] + w1 * fb[64 + l];
#pragma unroll
    for (int d = 1; d < 64; d <<= 1) ip += __shfl_xor(ip, d, 64);
    float it = sigm(ip + baiv);
    float a0 = fb[384 + l], a1 = fb[384 + 64 + l];
#pragma unroll
    for (int d2 = 0; d2 < 64; ++d2) {
      float s0 = rdl(d2 < 32 ? o0 : o1, (2 * d2) & 63);
      float s1 = rdl(d2 < 32 ? o0 : o1, (2 * d2 + 1) & 63);
      uint u0 = lds[d2 * 128 + l], u1 = lds[d2 * 128 + 64 + l];
      a0 += s0 * bl(u0) + s1 * bh(u0);
      a1 += s0 * bl(u1) + s1 * bh(u1);
    }
    float x0 = a0 * it + w0, x1 = a1 * it + w1;
    float smv = x0 + x1, sq = x0 * x0 + x1 * x1;
#pragma unroll
    for (int d = 1; d < 64; d <<= 1) { smv += __shfl_xor(smv, d, 64); sq += __shfl_xor(sq, d, 64); }
    float mn = smv * 0.0078125f;
    float var = sq * 0.0078125f - mn * mn;
    float rstd = rsqrtf(var + 1e-5f);
    float c0 = (x0 - mn) * rstd * fb[128 + l] + fb[256 + l];
    float c1 = (x1 - mn) * rstd * fb[128 + 64 + l] + fb[256 + 64 + l];
    float ob = fb[512 + l];
#pragma unroll
    for (int d2 = 0; d2 < 64; ++d2) {
      float s0 = rdl(d2 < 32 ? c0 : c1, (2 * d2) & 63);
      float s1 = rdl(d2 < 32 ? c0 : c1, (2 * d2 + 1) & 63);
      uint u = lds[8192 + d2 * 64 + l];
      ob += s0 * bl(u) + s1 * bh(u);
    }
    out[(size_t)tok * 64 + l] = ob;   // f32 output (reference output dtype)
  }
}

// ---------------------------------------------------------------------------
extern "C" void kernel_launch(void* const* d_in, const int* in_sizes, int n_in,
                              void* d_out, int out_size, void* d_ws, size_t ws_size,
                              hipStream_t stream)
{
  (void)out_size; (void)ws_size;
  float* ws = (float*)d_ws;
  uint* wsu = (uint*)d_ws;
  ushort* cb = (ushort*)(wsu + O_CAN);

  // canonical bf16 copies of all inputs (16B-aligned offsets)
  uint off[36]; uint cum = 0;
  for (int i = 0; i < 36; ++i) { off[i] = cum; cum = (cum + (uint)in_sizes[i] + 7u) & ~7u; }

  CVA ca;
  for (int i = 0; i < 36; ++i) ca.d[i] = CV{ d_in[i], off[i], (uint)in_sizes[i] };
  k_cvt<<<dim3(36, 16), 256, 0, stream>>>(ca, cb);

  const ushort* x        = cb + off[0];
  const ushort* W_in     = cb + off[1];
  const ushort* b_in     = cb + off[2];
  const ushort* W_l      = cb + off[3];
  const ushort* b_l      = cb + off[4];
  const ushort* g_l      = cb + off[5];
  const ushort* be_l     = cb + off[6];
  const ushort* W_ih     = cb + off[7];
  const ushort* W_hh     = cb + off[8];
  const ushort* b_ih     = cb + off[9];
  const ushort* b_hh     = cb + off[10];
  const ushort* mem0     = cb + off[11];
  const ushort* W_rh     = cb + off[12];
  const ushort* b_rh     = cb + off[13];
  const ushort* W_wh     = cb + off[14];
  const ushort* b_wh     = cb + off[15];
  const ushort* W_eh     = cb + off[16];
  const ushort* b_eh     = cb + off[17];
  const ushort* W_rg     = cb + off[18];
  const ushort* b_rg     = cb + off[19];
  const ushort* W_wg     = cb + off[20];
  const ushort* b_wg     = cb + off[21];
  const ushort* W_wm_qkv = cb + off[22];
  const ushort* b_wm_qkv = cb + off[23];
  const ushort* W_wm_o   = cb + off[24];
  const ushort* b_wm_o   = cb + off[25];
  const ushort* W_ca_qkv = cb + off[26];
  const ushort* b_ca_qkv = cb + off[27];
  const ushort* W_ca_o   = cb + off[28];
  const ushort* b_ca_o   = cb + off[29];
  const ushort* W_ai     = cb + off[30];
  const ushort* b_ai     = cb + off[31];
  const ushort* g_ca     = cb + off[32];
  const ushort* be_ca    = cb + off[33];
  const ushort* W_out    = cb + off[34];
  const ushort* b_out    = cb + off[35];

  k_wqcomb<<<64, 256, 0, stream>>>(W_wm_qkv, W_rh, b_rh, b_wm_qkv, (ushort*)(wsu + O_WQC16), ws + O_BQC);

  PA pa;
  pa.d[0]  = PD{ W_in,                       wsu + O_PWIN,  128, 32, 128, 0 };
  pa.d[1]  = PD{ W_l,                        wsu + O_PWL,   128, 64, 128, 0 };
  pa.d[2]  = PD{ W_l + 16384,                wsu + O_PWL + 8192,  128, 64, 128, 0 };
  pa.d[3]  = PD{ W_l + 32768,                wsu + O_PWL + 16384, 128, 64, 128, 0 };
  pa.d[4]  = PD{ W_ih,                       wsu + O_PWIH,  512, 64, 512, 0 };
  pa.d[5]  = PD{ W_wh,                       wsu + O_PCMB,  256, 64, 512, 0 };
  pa.d[6]  = PD{ W_eh,                       wsu + O_PCMB,  128, 64, 512, 256 };
  pa.d[7]  = PD{ (const ushort*)(wsu + O_WQC16), wsu + O_PCMB, 128, 64, 512, 384 };
  pa.d[8]  = PD{ W_ca_qkv,                   wsu + O_PQKV,  384, 64, 384, 0 };
  pa.d[9]  = PD{ W_ca_o,                     wsu + O_PWOC,  128, 64, 128, 0 };
  pa.d[10] = PD{ W_out,                      wsu + O_PWOUT,  64, 64,  64, 0 };
  pa.d[11] = PD{ W_wm_o,                     wsu + O_PWOWM, 128, 64, 128, 0 };
  k_pack<<<384, 256, 0, stream>>>(pa);
  k_whh<<<256, 256, 0, stream>>>(W_hh, ws + O_WHF);

  k_mlp<<<256, 256, 0, stream>>>(x, wsu + O_PWIN, b_in, b_l, g_l, be_l, ws + O_H);
  k_gates<<<256, 256, 0, stream>>>(ws + O_H, wsu + O_PWIH, b_ih, b_hh, ws + O_GX);
  k_lstm<<<16, 512, 0, stream>>>(ws + O_GX, ws + O_WHF, ws + O_HS);
  k_proj<<<256, 256, 0, stream>>>(ws + O_HS, wsu + O_PCMB, b_wh, b_eh, ws + O_BQC,
                                  W_rg, b_rg, W_wg, b_wg,
                                  ws + O_ST, ws + O_Q, ws + O_RGS);
  k_memrec<<<16, 64, 0, stream>>>(ws + O_ST, mem0, ws + O_EW);
  k_snap<<<128, 256, 0, stream>>>(ws + O_ST, ws + O_EW, mem0, wsu + O_MEMA);
  k_read<<<1024, 256, 0, stream>>>(W_wm_qkv, b_wm_o, wsu + O_PWOWM, wsu + O_MEMA,
                                   ws + O_Q, ws + O_RGS, ws + O_H, ws + O_WM);
  k_caqkv<<<256, 256, 0, stream>>>(ws + O_WM, wsu + O_PQKV, b_ca_qkv, ws + O_QCA, ws + O_KCA, ws + O_VCA);
  k_caattn<<<256, 256, 0, stream>>>(ws + O_QCA, ws + O_KCA, ws + O_VCA, ws + O_AO);
  k_cafinal<<<256, 256, 0, stream>>>(ws + O_WM, ws + O_AO, wsu + O_PWOC, wsu + O_PWOUT,
                                     W_ai, b_ai, g_ca, be_ca, b_ca_o, b_out, (float*)d_out);
}